// Round 6
// baseline (395.069 us; speedup 1.0000x reference)
//
#include <hip/hip_runtime.h>
#include <math.h>

typedef unsigned int u32;

#define NN   40000
#define EE   640000
#define FD   128
#define HD   128
#define SUBG 400
#define CELLS 100
#define BNEPS 1e-5f
#define NPB  157   // ceil(NN/256)
#define STATB 160  // bnstats blocks

// ---- bf16 helpers (pack with RNE, unpack via bit-shift) ----
__device__ __forceinline__ u32 bf16pair(float a, float b) {
    u32 ua = __float_as_uint(a), ub = __float_as_uint(b);
    ua += 0x7fffu + ((ua >> 16) & 1u);
    ub += 0x7fffu + ((ub >> 16) & 1u);
    return (ua >> 16) | (ub & 0xffff0000u);
}
__device__ __forceinline__ float bflo(u32 u) { return __uint_as_float(u << 16); }
__device__ __forceinline__ float bfhi(u32 u) { return __uint_as_float(u & 0xffff0000u); }

// ---------------- CSR build ----------------
__global__ void k_zeroi(int* p, int n) {
    int i = blockIdx.x * blockDim.x + threadIdx.x;
    if (i < n) p[i] = 0;
}

__global__ void k_degcount(const int* __restrict__ dst, int* __restrict__ deg) {
    int i = blockIdx.x * blockDim.x + threadIdx.x;
    int stride = gridDim.x * blockDim.x;
    for (; i < EE; i += stride) atomicAdd(&deg[dst[i]], 1);
}

__global__ void k_scan1(const int* __restrict__ deg, int* __restrict__ excl,
                        int* __restrict__ part) {
    __shared__ int s[256];
    int t = threadIdx.x;
    int i = blockIdx.x * 256 + t;
    int v = (i < NN) ? deg[i] : 0;
    s[t] = v;
    __syncthreads();
    for (int off = 1; off < 256; off <<= 1) {
        int add = (t >= off) ? s[t - off] : 0;
        __syncthreads();
        s[t] += add;
        __syncthreads();
    }
    if (i < NN) excl[i] = s[t] - v;
    if (t == 255) part[blockIdx.x] = s[255];
}

__global__ void k_scan2(int* __restrict__ part, int* __restrict__ partx) {
    __shared__ int s[256];
    int t = threadIdx.x;
    int v = (t < NPB) ? part[t] : 0;
    s[t] = v;
    __syncthreads();
    for (int off = 1; off < 256; off <<= 1) {
        int add = (t >= off) ? s[t - off] : 0;
        __syncthreads();
        s[t] += add;
        __syncthreads();
    }
    if (t < NPB) partx[t] = s[t] - v;
}

__global__ void k_scan3(const int* __restrict__ excl, const int* __restrict__ partx,
                        const int* __restrict__ deg, int* __restrict__ rowstart,
                        float* __restrict__ dis) {
    int i = blockIdx.x * 256 + threadIdx.x;
    if (i < NN) {
        rowstart[i] = excl[i] + partx[blockIdx.x];
        dis[i] = rsqrtf((float)(deg[i] + 1));   // +1 self-loop
    }
    if (i == 0) rowstart[NN] = EE;
}

__global__ void k_fill(const int* __restrict__ src, const int* __restrict__ dst,
                       const int* __restrict__ rowstart, int* __restrict__ cursor,
                       int* __restrict__ csr_src) {
    int i = blockIdx.x * blockDim.x + threadIdx.x;
    int stride = gridDim.x * blockDim.x;
    for (; i < EE; i += stride) {
        int d = dst[i];
        int slot = rowstart[d] + atomicAdd(&cursor[d], 1);
        csr_src[slot] = src[i];
    }
}

// ---------------- tiled GEMM  Yb[M,128](bf16) = dis[r] * (X[M,128] @ W[128,128]) ----------------
// 64-row LDS tile float4[64][32] linear; thread = 8 rows x 4 cols, float4 acc[8].
// Optional fused input BN+ReLU during staging (ss != nullptr).
// Output rows pre-scaled by dis[row] and packed bf16 (for the gather).
__global__ __launch_bounds__(256, 2)
void k_gemm128(const float* __restrict__ X, const float* __restrict__ W,
               u32* __restrict__ Yb, const float* __restrict__ ss,
               const float* __restrict__ dis) {
    __shared__ float4 xs[64 * 32];   // 32 KB
    int t = threadIdx.x;
    long rowbase = (long)blockIdx.x * 64;
    const float4* Xv = (const float4*)(X + rowbase * 128);
    if (ss) {
#pragma unroll
        for (int i = 0; i < 8; ++i) {
            int f = t + 256 * i;
            int c4 = (f & 31) * 4;
            float4 v = Xv[f];
            float4 sc = *(const float4*)&ss[c4];
            float4 sh = *(const float4*)&ss[128 + c4];
            v.x = fmaxf(fmaf(v.x, sc.x, sh.x), 0.f);
            v.y = fmaxf(fmaf(v.y, sc.y, sh.y), 0.f);
            v.z = fmaxf(fmaf(v.z, sc.z, sh.z), 0.f);
            v.w = fmaxf(fmaf(v.w, sc.w, sh.w), 0.f);
            xs[f] = v;
        }
    } else {
#pragma unroll
        for (int i = 0; i < 8; ++i)
            xs[t + 256 * i] = Xv[t + 256 * i];
    }
    __syncthreads();

    int cg = t & 31;            // col group: cols cg*4 .. cg*4+3
    int r0 = (t >> 5) * 8;      // 8 rows
    const float4* Wv = (const float4*)W;

    float4 acc[8];
#pragma unroll
    for (int i = 0; i < 8; ++i) acc[i] = make_float4(0.f, 0.f, 0.f, 0.f);

    for (int k4 = 0; k4 < 32; ++k4) {
        float4 w0 = Wv[(4 * k4 + 0) * 32 + cg];
        float4 w1 = Wv[(4 * k4 + 1) * 32 + cg];
        float4 w2 = Wv[(4 * k4 + 2) * 32 + cg];
        float4 w3 = Wv[(4 * k4 + 3) * 32 + cg];
#pragma unroll
        for (int i = 0; i < 8; ++i) {
            float4 xv = xs[(r0 + i) * 32 + k4];
            acc[i].x = fmaf(xv.x, w0.x, acc[i].x);
            acc[i].x = fmaf(xv.y, w1.x, acc[i].x);
            acc[i].x = fmaf(xv.z, w2.x, acc[i].x);
            acc[i].x = fmaf(xv.w, w3.x, acc[i].x);
            acc[i].y = fmaf(xv.x, w0.y, acc[i].y);
            acc[i].y = fmaf(xv.y, w1.y, acc[i].y);
            acc[i].y = fmaf(xv.z, w2.y, acc[i].y);
            acc[i].y = fmaf(xv.w, w3.y, acc[i].y);
            acc[i].z = fmaf(xv.x, w0.z, acc[i].z);
            acc[i].z = fmaf(xv.y, w1.z, acc[i].z);
            acc[i].z = fmaf(xv.z, w2.z, acc[i].z);
            acc[i].z = fmaf(xv.w, w3.z, acc[i].z);
            acc[i].w = fmaf(xv.x, w0.w, acc[i].w);
            acc[i].w = fmaf(xv.y, w1.w, acc[i].w);
            acc[i].w = fmaf(xv.z, w2.w, acc[i].w);
            acc[i].w = fmaf(xv.w, w3.w, acc[i].w);
        }
    }
    u32* yout = Yb + (rowbase + r0) * 64 + cg * 2;
#pragma unroll
    for (int i = 0; i < 8; ++i) {
        float dd = dis[rowbase + r0 + i];
        uint2 p;
        p.x = bf16pair(acc[i].x * dd, acc[i].y * dd);
        p.y = bf16pair(acc[i].z * dd, acc[i].w * dd);
        *(uint2*)&yout[i * 64] = p;
    }
}

// ---------------- GCN aggregation: bf16 CSR gather over pre-scaled rows ----------------
// Hb rows are H'[s] = dis[s]*H[s].  out[d,:] = dis[d]*( sum_{s in N(d)} H'[s] + H'[d] ) + bias
// Wave = 1 node, 4 groups x 16 lanes; lane loads uint4 (16B) -> 1KB per VMEM instr.
__global__ void k_gather(const uint4* __restrict__ Hb, const int* __restrict__ rowstart,
                         const int* __restrict__ csr_src, const float* __restrict__ dis,
                         const float* __restrict__ bias, float* __restrict__ out) {
    int lane = threadIdx.x & 63;
    int node = (blockIdx.x * blockDim.x + threadIdx.x) >> 6;
    if (node >= NN) return;
    int g = lane >> 4, p = lane & 15;
    float a0 = 0.f, a1 = 0.f, a2 = 0.f, a3 = 0.f, a4 = 0.f, a5 = 0.f, a6 = 0.f, a7 = 0.f;
    if (g == 0) {   // self-loop term, counted once (summed into group 0's partial)
        uint4 h = Hb[node * 16 + p];
        a0 = bflo(h.x); a1 = bfhi(h.x);
        a2 = bflo(h.y); a3 = bfhi(h.y);
        a4 = bflo(h.z); a5 = bfhi(h.z);
        a6 = bflo(h.w); a7 = bfhi(h.w);
    }
    int e1 = rowstart[node + 1];
    int e = rowstart[node] + g;
    for (; e + 4 < e1; e += 8) {     // 2 edges per group in flight
        int s0 = csr_src[e];
        int s1 = csr_src[e + 4];
        uint4 h0 = Hb[s0 * 16 + p];
        uint4 h1 = Hb[s1 * 16 + p];
        a0 += bflo(h0.x); a1 += bfhi(h0.x);
        a2 += bflo(h0.y); a3 += bfhi(h0.y);
        a4 += bflo(h0.z); a5 += bfhi(h0.z);
        a6 += bflo(h0.w); a7 += bfhi(h0.w);
        a0 += bflo(h1.x); a1 += bfhi(h1.x);
        a2 += bflo(h1.y); a3 += bfhi(h1.y);
        a4 += bflo(h1.z); a5 += bfhi(h1.z);
        a6 += bflo(h1.w); a7 += bfhi(h1.w);
    }
    if (e < e1) {
        int s0 = csr_src[e];
        uint4 h0 = Hb[s0 * 16 + p];
        a0 += bflo(h0.x); a1 += bfhi(h0.x);
        a2 += bflo(h0.y); a3 += bfhi(h0.y);
        a4 += bflo(h0.z); a5 += bfhi(h0.z);
        a6 += bflo(h0.w); a7 += bfhi(h0.w);
    }
    // reduce across the 4 groups (lane bits 4,5)
#pragma unroll
    for (int m = 16; m <= 32; m <<= 1) {
        a0 += __shfl_xor(a0, m); a1 += __shfl_xor(a1, m);
        a2 += __shfl_xor(a2, m); a3 += __shfl_xor(a3, m);
        a4 += __shfl_xor(a4, m); a5 += __shfl_xor(a5, m);
        a6 += __shfl_xor(a6, m); a7 += __shfl_xor(a7, m);
    }
    float dd = dis[node];
    int c0 = p * 8 + g * 2;          // this lane writes 2 cols of the 512B row
    float x = (g == 0) ? a0 : (g == 1) ? a2 : (g == 2) ? a4 : a6;
    float y = (g == 0) ? a1 : (g == 1) ? a3 : (g == 2) ? a5 : a7;
    float2 b2 = *(const float2*)&bias[c0];
    float2 o = { fmaf(x, dd, b2.x), fmaf(y, dd, b2.y) };
    *(float2*)&out[(long)node * 128 + c0] = o;
}

// ---------------- BatchNorm stats: per-block partials (no atomics) ----------------
__global__ void k_bnstats(const float* __restrict__ X, float* __restrict__ part,
                          int rowsPerBlock) {
    __shared__ float ls[256], ls2[256];
    int t = threadIdx.x;
    int col = t & 127, half = t >> 7;
    int r0 = blockIdx.x * rowsPerBlock;
    int r1 = r0 + rowsPerBlock; if (r1 > NN) r1 = NN;
    float s = 0.f, s2 = 0.f;
    for (int r = r0 + half; r < r1; r += 2) {
        float v = X[(long)r * 128 + col];
        s += v; s2 += v * v;
    }
    ls[t] = s; ls2[t] = s2;
    __syncthreads();
    if (t < 128) {
        part[blockIdx.x * 256 + t]       = ls[t]  + ls[t + 128];
        part[blockIdx.x * 256 + 128 + t] = ls2[t] + ls2[t + 128];
    }
}

__global__ void k_bnfinal(const float* __restrict__ part, const float* __restrict__ g,
                          const float* __restrict__ b, float* __restrict__ ss) {
    __shared__ float acc[512];
    int t = threadIdx.x;           // 256
    int c = t & 127, half = t >> 7;
    float s = 0.f, s2 = 0.f;
    for (int bb = half; bb < STATB; bb += 2) {
        s  += part[bb * 256 + c];
        s2 += part[bb * 256 + 128 + c];
    }
    acc[t] = s; acc[256 + t] = s2;
    __syncthreads();
    if (t < 128) {
        float S  = acc[t] + acc[t + 128];
        float S2 = acc[256 + t] + acc[256 + t + 128];
        float mean = S * (1.0f / NN);
        float var  = S2 * (1.0f / NN) - mean * mean;
        float scale = g[t] * rsqrtf(var + BNEPS);
        ss[t] = scale;
        ss[128 + t] = b[t] - mean * scale;
    }
}

// ---------------- fused BN2+ReLU + emb write + attention scores ----------------
__global__ __launch_bounds__(256, 2)
void k_scores(const float* __restrict__ X, const float* __restrict__ ss,
              float* __restrict__ emb,
              const float* __restrict__ w1, const float* __restrict__ b1,
              const float* __restrict__ w2, const float* __restrict__ b2,
              float* __restrict__ scores) {
    __shared__ float4 xs[64 * 32];  // 32 KB
    int t = threadIdx.x;
    long rowbase = (long)blockIdx.x * 64;
    const float4* Xv = (const float4*)(X + rowbase * 128);
    float4* Ev = (float4*)(emb + rowbase * 128);
#pragma unroll
    for (int i = 0; i < 8; ++i) {
        int f = t + 256 * i;
        int c4 = (f & 31) * 4;
        float4 v = Xv[f];
        float4 sc = *(const float4*)&ss[c4];
        float4 sh = *(const float4*)&ss[128 + c4];
        v.x = fmaxf(fmaf(v.x, sc.x, sh.x), 0.f);
        v.y = fmaxf(fmaf(v.y, sc.y, sh.y), 0.f);
        v.z = fmaxf(fmaf(v.z, sc.z, sh.z), 0.f);
        v.w = fmaxf(fmaf(v.w, sc.w, sh.w), 0.f);
        Ev[f] = v;
        xs[f] = v;
    }
    __syncthreads();

    int cg = t & 15;            // col group: cols cg*4 .. +3 (of 64)
    int r0 = (t >> 4) * 4;      // 4 rows
    const float4* Wv = (const float4*)w1;
    float4 bb = ((const float4*)b1)[cg];

    float4 acc[4];
#pragma unroll
    for (int i = 0; i < 4; ++i) acc[i] = bb;

    for (int k4 = 0; k4 < 32; ++k4) {
        float4 w0 = Wv[(4 * k4 + 0) * 16 + cg];
        float4 w1v = Wv[(4 * k4 + 1) * 16 + cg];
        float4 w2v = Wv[(4 * k4 + 2) * 16 + cg];
        float4 w3 = Wv[(4 * k4 + 3) * 16 + cg];
#pragma unroll
        for (int i = 0; i < 4; ++i) {
            float4 xv = xs[(r0 + i) * 32 + k4];
            acc[i].x = fmaf(xv.x, w0.x, acc[i].x);
            acc[i].x = fmaf(xv.y, w1v.x, acc[i].x);
            acc[i].x = fmaf(xv.z, w2v.x, acc[i].x);
            acc[i].x = fmaf(xv.w, w3.x, acc[i].x);
            acc[i].y = fmaf(xv.x, w0.y, acc[i].y);
            acc[i].y = fmaf(xv.y, w1v.y, acc[i].y);
            acc[i].y = fmaf(xv.z, w2v.y, acc[i].y);
            acc[i].y = fmaf(xv.w, w3.y, acc[i].y);
            acc[i].z = fmaf(xv.x, w0.z, acc[i].z);
            acc[i].z = fmaf(xv.y, w1v.z, acc[i].z);
            acc[i].z = fmaf(xv.z, w2v.z, acc[i].z);
            acc[i].z = fmaf(xv.w, w3.z, acc[i].z);
            acc[i].w = fmaf(xv.x, w0.w, acc[i].w);
            acc[i].w = fmaf(xv.y, w1v.w, acc[i].w);
            acc[i].w = fmaf(xv.z, w2v.w, acc[i].w);
            acc[i].w = fmaf(xv.w, w3.w, acc[i].w);
        }
    }
    float4 w2v = ((const float4*)w2)[cg];
    float b2v = b2[0];
#pragma unroll
    for (int i = 0; i < 4; ++i) {
        float v = tanhf(acc[i].x) * w2v.x + tanhf(acc[i].y) * w2v.y
                + tanhf(acc[i].z) * w2v.z + tanhf(acc[i].w) * w2v.w;
        v += __shfl_xor(v, 1);
        v += __shfl_xor(v, 2);
        v += __shfl_xor(v, 4);
        v += __shfl_xor(v, 8);
        if (cg == 0) scores[rowbase + r0 + i] = v + b2v;
    }
}

// ---------------- softmax over genes within cell + weighted pool ----------------
__global__ void k_pool(const float* __restrict__ emb, const float* __restrict__ scores,
                       float* __restrict__ pooled) {
    __shared__ float sl[SUBG];
    __shared__ float red[512];
    int c = blockIdx.x;
    int t = threadIdx.x;   // 512 threads
    int base = c * SUBG;
    float lmax = -1e30f;
    for (int i = t; i < SUBG; i += 512) {
        float v = scores[base + i];
        sl[i] = v;
        lmax = fmaxf(lmax, v);
    }
    red[t] = lmax; __syncthreads();
    for (int off = 256; off > 0; off >>= 1) {
        if (t < off) red[t] = fmaxf(red[t], red[t + off]);
        __syncthreads();
    }
    float mx = red[0]; __syncthreads();
    float lsum = 0.f;
    for (int i = t; i < SUBG; i += 512) {
        float e = __expf(sl[i] - mx);
        sl[i] = e;
        lsum += e;
    }
    red[t] = lsum; __syncthreads();
    for (int off = 256; off > 0; off >>= 1) {
        if (t < off) red[t] += red[t + off];
        __syncthreads();
    }
    float inv = 1.0f / red[0];
    __syncthreads();
    int col = t & 127, grp = t >> 7;   // 4 row-groups
    float acc = 0.f;
#pragma unroll 2
    for (int s = grp; s < SUBG; s += 4)
        acc += sl[s] * emb[(long)(base + s) * 128 + col];
    red[t] = acc; __syncthreads();
    if (grp == 0)
        pooled[c * 128 + col] = (red[col] + red[128 + col] + red[256 + col] + red[384 + col]) * inv;
}

// ---------------- fused dense head: fc+BN+ReLU -> bottleneck+BN+ReLU ----------------
// Single block, 512 threads; intermediates in registers/LDS.
__global__ __launch_bounds__(512)
void k_head(const float* __restrict__ pooled,
            const float* __restrict__ fc_w, const float* __restrict__ fc_b,
            const float* __restrict__ bne_g, const float* __restrict__ bne_b,
            const float* __restrict__ bot_w, const float* __restrict__ bot_b,
            const float* __restrict__ bnb_g, const float* __restrict__ bnb_b,
            float* __restrict__ y_out) {
    __shared__ float P[CELLS * 128];   // pooled, then y1 (post BN+ReLU)  51.2 KB
    __shared__ float red[512], red2[512];
    int t = threadIdx.x;
    for (int i = t; i < CELLS * 128; i += 512) P[i] = pooled[i];
    __syncthreads();

    int col = t & 127, cp = t >> 7;    // 4 cell-groups of 25 cells
    float r1[25];
    float fb = fc_b[col];
#pragma unroll
    for (int j = 0; j < 25; ++j) {
        int c = cp + 4 * j;
        float acc = fb;
        for (int k = 0; k < 128; ++k)
            acc = fmaf(P[c * 128 + k], fc_w[k * 128 + col], acc);
        r1[j] = acc;
    }
    float s = 0.f, s2 = 0.f;
#pragma unroll
    for (int j = 0; j < 25; ++j) { s += r1[j]; s2 += r1[j] * r1[j]; }
    red[t] = s; red2[t] = s2;
    __syncthreads();
    if (t < 128) {
        float S  = red[t] + red[t + 128] + red[t + 256] + red[t + 384];
        float S2 = red2[t] + red2[t + 128] + red2[t + 256] + red2[t + 384];
        float mean = S * 0.01f, var = S2 * 0.01f - mean * mean;
        float sc = bne_g[t] * rsqrtf(var + BNEPS);
        red[t] = sc; red2[t] = bne_b[t] - mean * sc;
    }
    __syncthreads();
    float sc1 = red[col], sh1 = red2[col];
#pragma unroll
    for (int j = 0; j < 25; ++j)
        P[(cp + 4 * j) * 128 + col] = fmaxf(fmaf(r1[j], sc1, sh1), 0.f);
    __syncthreads();

    // bottleneck 128 -> 32
    int col2 = t & 31, c2 = t >> 5;    // 16 cell-groups of <=7 cells
    float r2[7];
    float bb = bot_b[col2];
#pragma unroll
    for (int j = 0; j < 7; ++j) {
        int c = c2 + 16 * j;
        float acc = bb;
        if (c < CELLS) {
            for (int k = 0; k < 128; ++k)
                acc = fmaf(P[c * 128 + k], bot_w[k * 32 + col2], acc);
        }
        r2[j] = acc;
    }
    float u = 0.f, u2 = 0.f;
#pragma unroll
    for (int j = 0; j < 7; ++j) {
        int c = c2 + 16 * j;
        if (c < CELLS) { u += r2[j]; u2 += r2[j] * r2[j]; }
    }
    red[t] = u; red2[t] = u2;
    __syncthreads();
    if (t < 32) {
        float S = 0.f, S2 = 0.f;
        for (int g2 = 0; g2 < 16; ++g2) { S += red[g2 * 32 + t]; S2 += red2[g2 * 32 + t]; }
        float mean = S * 0.01f, var = S2 * 0.01f - mean * mean;
        float sc = bnb_g[t] * rsqrtf(var + BNEPS);
        red[t] = sc; red2[t] = bnb_b[t] - mean * sc;
    }
    __syncthreads();
    float sc2 = red[col2], sh2 = red2[col2];
#pragma unroll
    for (int j = 0; j < 7; ++j) {
        int c = c2 + 16 * j;
        if (c < CELLS) y_out[c * 32 + col2] = fmaxf(fmaf(r2[j], sc2, sh2), 0.f);
    }
}

// ---------------- launcher ----------------
extern "C" void kernel_launch(void* const* d_in, const int* in_sizes, int n_in,
                              void* d_out, int out_size, void* d_ws, size_t ws_size,
                              hipStream_t stream) {
    const float* x        = (const float*)d_in[0];
    const int*   ei       = (const int*)d_in[1];
    const float* conv1_w  = (const float*)d_in[2];
    const float* conv1_b  = (const float*)d_in[3];
    const float* bn1_g    = (const float*)d_in[4];
    const float* bn1_b    = (const float*)d_in[5];
    const float* conv2_w  = (const float*)d_in[6];
    const float* conv2_b  = (const float*)d_in[7];
    const float* bn2_g    = (const float*)d_in[8];
    const float* bn2_b    = (const float*)d_in[9];
    const float* att_w1   = (const float*)d_in[10];
    const float* att_b1   = (const float*)d_in[11];
    const float* att_w2   = (const float*)d_in[12];
    const float* att_b2   = (const float*)d_in[13];
    const float* fc_w     = (const float*)d_in[14];
    const float* fc_b     = (const float*)d_in[15];
    const float* bne_g    = (const float*)d_in[16];
    const float* bne_b    = (const float*)d_in[17];
    const float* bot_w    = (const float*)d_in[18];
    const float* bot_b    = (const float*)d_in[19];
    const float* bnb_g    = (const float*)d_in[20];
    const float* bnb_b    = (const float*)d_in[21];

    const int* src = ei;
    const int* dst = ei + EE;

    float* y_out   = (float*)d_out;            // [100,32]
    float* emb_out = y_out + CELLS * 32;       // [40000,128]

    float* ws = (float*)d_ws;
    float* F1     = ws;                              // N*H f32 (20.5 MB)
    u32*   Hb     = (u32*)(ws + (long)NN * HD);      // N*64 u32 (bf16 H', 10.25 MB)
    float* fbase  = ws + (long)NN * HD + (long)NN * 64;
    float* dis    = fbase;                     // N
    float* scores = dis + NN;                  // N
    float* part   = scores + NN;               // STATB*256
    float* sstats = part + STATB * 256;        // 256
    float* pooled = sstats + 256;              // C*H
    int* ibase    = (int*)(pooled + CELLS * HD);
    int* deg      = ibase;                     // N
    int* cursor   = deg + NN;                  // N
    int* excl     = cursor + NN;               // N
    int* rowstart = excl + NN;                 // N+1
    int* partsc   = rowstart + NN + 1;         // NPB
    int* partx    = partsc + NPB;              // NPB
    int* csr_src  = partx + NPB;               // E

    // ---- CSR build (shared by both convs) ----
    k_zeroi<<<(2 * NN + 255) / 256, 256, 0, stream>>>(deg, 2 * NN);
    k_degcount<<<1024, 256, 0, stream>>>(dst, deg);
    k_scan1<<<NPB, 256, 0, stream>>>(deg, excl, partsc);
    k_scan2<<<1, 256, 0, stream>>>(partsc, partx);
    k_scan3<<<NPB, 256, 0, stream>>>(excl, partx, deg, rowstart, dis);
    k_fill<<<2048, 256, 0, stream>>>(src, dst, rowstart, cursor, csr_src);

    // ---- conv1 ----
    k_gemm128<<<625, 256, 0, stream>>>(x, conv1_w, Hb, nullptr, dis);
    k_gather<<<10000, 256, 0, stream>>>((const uint4*)Hb, rowstart, csr_src, dis, conv1_b, F1);
    k_bnstats<<<STATB, 256, 0, stream>>>(F1, part, 250);
    k_bnfinal<<<1, 256, 0, stream>>>(part, bn1_g, bn1_b, sstats);

    // ---- conv2 (BN1+ReLU fused into GEMM staging) ----
    k_gemm128<<<625, 256, 0, stream>>>(F1, conv2_w, Hb, sstats, dis);
    k_gather<<<10000, 256, 0, stream>>>((const uint4*)Hb, rowstart, csr_src, dis, conv2_b, F1);
    k_bnstats<<<STATB, 256, 0, stream>>>(F1, part, 250);
    k_bnfinal<<<1, 256, 0, stream>>>(part, bn2_g, bn2_b, sstats);

    // ---- BN2+ReLU + emb write + attention scores (fused) ----
    k_scores<<<625, 256, 0, stream>>>(F1, sstats, emb_out, att_w1, att_b1, att_w2, att_b2, scores);
    k_pool<<<CELLS, 512, 0, stream>>>(emb_out, scores, pooled);

    // ---- fused head ----
    k_head<<<1, 512, 0, stream>>>(pooled, fc_w, fc_b, bne_g, bne_b,
                                  bot_w, bot_b, bnb_g, bnb_b, y_out);
}

// Round 7
// 363.412 us; speedup vs baseline: 1.0871x; 1.0871x over previous
//
#include <hip/hip_runtime.h>
#include <math.h>

typedef unsigned int u32;

#define NN   40000
#define EE   640000
#define FD   128
#define HD   128
#define SUBG 400
#define CELLS 100
#define BNEPS 1e-5f
#define NPB  157   // ceil(NN/256)
#define STATB 160  // bnstats blocks

// ---- bf16 helpers (pack with RNE, unpack via bit-shift) ----
__device__ __forceinline__ u32 bf16pair(float a, float b) {
    u32 ua = __float_as_uint(a), ub = __float_as_uint(b);
    ua += 0x7fffu + ((ua >> 16) & 1u);
    ub += 0x7fffu + ((ub >> 16) & 1u);
    return (ua >> 16) | (ub & 0xffff0000u);
}
__device__ __forceinline__ float bflo(u32 u) { return __uint_as_float(u << 16); }
__device__ __forceinline__ float bfhi(u32 u) { return __uint_as_float(u & 0xffff0000u); }

// ---------------- CSR build ----------------
__global__ void k_zeroi(int* p, int n) {
    int i = blockIdx.x * blockDim.x + threadIdx.x;
    if (i < n) p[i] = 0;
}

__global__ void k_degcount(const int* __restrict__ dst, int* __restrict__ deg) {
    int i = blockIdx.x * blockDim.x + threadIdx.x;
    int stride = gridDim.x * blockDim.x;
    for (; i < EE; i += stride) atomicAdd(&deg[dst[i]], 1);
}

__global__ void k_scan1(const int* __restrict__ deg, int* __restrict__ excl,
                        int* __restrict__ part) {
    __shared__ int s[256];
    int t = threadIdx.x;
    int i = blockIdx.x * 256 + t;
    int v = (i < NN) ? deg[i] : 0;
    s[t] = v;
    __syncthreads();
    for (int off = 1; off < 256; off <<= 1) {
        int add = (t >= off) ? s[t - off] : 0;
        __syncthreads();
        s[t] += add;
        __syncthreads();
    }
    if (i < NN) excl[i] = s[t] - v;
    if (t == 255) part[blockIdx.x] = s[255];
}

__global__ void k_scan2(int* __restrict__ part, int* __restrict__ partx) {
    __shared__ int s[256];
    int t = threadIdx.x;
    int v = (t < NPB) ? part[t] : 0;
    s[t] = v;
    __syncthreads();
    for (int off = 1; off < 256; off <<= 1) {
        int add = (t >= off) ? s[t - off] : 0;
        __syncthreads();
        s[t] += add;
        __syncthreads();
    }
    if (t < NPB) partx[t] = s[t] - v;
}

__global__ void k_scan3(const int* __restrict__ excl, const int* __restrict__ partx,
                        const int* __restrict__ deg, int* __restrict__ rowstart,
                        float* __restrict__ dis) {
    int i = blockIdx.x * 256 + threadIdx.x;
    if (i < NN) {
        rowstart[i] = excl[i] + partx[blockIdx.x];
        dis[i] = rsqrtf((float)(deg[i] + 1));   // +1 self-loop
    }
    if (i == 0) rowstart[NN] = EE;
}

__global__ void k_fill(const int* __restrict__ src, const int* __restrict__ dst,
                       const int* __restrict__ rowstart, int* __restrict__ cursor,
                       int* __restrict__ csr_src) {
    int i = blockIdx.x * blockDim.x + threadIdx.x;
    int stride = gridDim.x * blockDim.x;
    for (; i < EE; i += stride) {
        int d = dst[i];
        int slot = rowstart[d] + atomicAdd(&cursor[d], 1);
        csr_src[slot] = src[i];
    }
}

// ---------------- tiled GEMM  Yb[M,128](bf16) = dis[r] * (X[M,128] @ W[128,128]) ----------------
__global__ __launch_bounds__(256, 2)
void k_gemm128(const float* __restrict__ X, const float* __restrict__ W,
               u32* __restrict__ Yb, const float* __restrict__ ss,
               const float* __restrict__ dis) {
    __shared__ float4 xs[64 * 32];   // 32 KB
    int t = threadIdx.x;
    long rowbase = (long)blockIdx.x * 64;
    const float4* Xv = (const float4*)(X + rowbase * 128);
    if (ss) {
#pragma unroll
        for (int i = 0; i < 8; ++i) {
            int f = t + 256 * i;
            int c4 = (f & 31) * 4;
            float4 v = Xv[f];
            float4 sc = *(const float4*)&ss[c4];
            float4 sh = *(const float4*)&ss[128 + c4];
            v.x = fmaxf(fmaf(v.x, sc.x, sh.x), 0.f);
            v.y = fmaxf(fmaf(v.y, sc.y, sh.y), 0.f);
            v.z = fmaxf(fmaf(v.z, sc.z, sh.z), 0.f);
            v.w = fmaxf(fmaf(v.w, sc.w, sh.w), 0.f);
            xs[f] = v;
        }
    } else {
#pragma unroll
        for (int i = 0; i < 8; ++i)
            xs[t + 256 * i] = Xv[t + 256 * i];
    }
    __syncthreads();

    int cg = t & 31;            // col group: cols cg*4 .. cg*4+3
    int r0 = (t >> 5) * 8;      // 8 rows
    const float4* Wv = (const float4*)W;

    float4 acc[8];
#pragma unroll
    for (int i = 0; i < 8; ++i) acc[i] = make_float4(0.f, 0.f, 0.f, 0.f);

    for (int k4 = 0; k4 < 32; ++k4) {
        float4 w0 = Wv[(4 * k4 + 0) * 32 + cg];
        float4 w1 = Wv[(4 * k4 + 1) * 32 + cg];
        float4 w2 = Wv[(4 * k4 + 2) * 32 + cg];
        float4 w3 = Wv[(4 * k4 + 3) * 32 + cg];
#pragma unroll
        for (int i = 0; i < 8; ++i) {
            float4 xv = xs[(r0 + i) * 32 + k4];
            acc[i].x = fmaf(xv.x, w0.x, acc[i].x);
            acc[i].x = fmaf(xv.y, w1.x, acc[i].x);
            acc[i].x = fmaf(xv.z, w2.x, acc[i].x);
            acc[i].x = fmaf(xv.w, w3.x, acc[i].x);
            acc[i].y = fmaf(xv.x, w0.y, acc[i].y);
            acc[i].y = fmaf(xv.y, w1.y, acc[i].y);
            acc[i].y = fmaf(xv.z, w2.y, acc[i].y);
            acc[i].y = fmaf(xv.w, w3.y, acc[i].y);
            acc[i].z = fmaf(xv.x, w0.z, acc[i].z);
            acc[i].z = fmaf(xv.y, w1.z, acc[i].z);
            acc[i].z = fmaf(xv.z, w2.z, acc[i].z);
            acc[i].z = fmaf(xv.w, w3.z, acc[i].z);
            acc[i].w = fmaf(xv.x, w0.w, acc[i].w);
            acc[i].w = fmaf(xv.y, w1.w, acc[i].w);
            acc[i].w = fmaf(xv.z, w2.w, acc[i].w);
            acc[i].w = fmaf(xv.w, w3.w, acc[i].w);
        }
    }
    u32* yout = Yb + (rowbase + r0) * 64 + cg * 2;
#pragma unroll
    for (int i = 0; i < 8; ++i) {
        float dd = dis[rowbase + r0 + i];
        uint2 p;
        p.x = bf16pair(acc[i].x * dd, acc[i].y * dd);
        p.y = bf16pair(acc[i].z * dd, acc[i].w * dd);
        *(uint2*)&yout[i * 64] = p;
    }
}

// ---------------- GCN aggregation: bf16 CSR gather over pre-scaled rows ----------------
__global__ void k_gather(const uint4* __restrict__ Hb, const int* __restrict__ rowstart,
                         const int* __restrict__ csr_src, const float* __restrict__ dis,
                         const float* __restrict__ bias, float* __restrict__ out) {
    int lane = threadIdx.x & 63;
    int node = (blockIdx.x * blockDim.x + threadIdx.x) >> 6;
    if (node >= NN) return;
    int g = lane >> 4, p = lane & 15;
    float a0 = 0.f, a1 = 0.f, a2 = 0.f, a3 = 0.f, a4 = 0.f, a5 = 0.f, a6 = 0.f, a7 = 0.f;
    if (g == 0) {   // self-loop term, counted once
        uint4 h = Hb[node * 16 + p];
        a0 = bflo(h.x); a1 = bfhi(h.x);
        a2 = bflo(h.y); a3 = bfhi(h.y);
        a4 = bflo(h.z); a5 = bfhi(h.z);
        a6 = bflo(h.w); a7 = bfhi(h.w);
    }
    int e1 = rowstart[node + 1];
    int e = rowstart[node] + g;
    for (; e + 4 < e1; e += 8) {
        int s0 = csr_src[e];
        int s1 = csr_src[e + 4];
        uint4 h0 = Hb[s0 * 16 + p];
        uint4 h1 = Hb[s1 * 16 + p];
        a0 += bflo(h0.x); a1 += bfhi(h0.x);
        a2 += bflo(h0.y); a3 += bfhi(h0.y);
        a4 += bflo(h0.z); a5 += bfhi(h0.z);
        a6 += bflo(h0.w); a7 += bfhi(h0.w);
        a0 += bflo(h1.x); a1 += bfhi(h1.x);
        a2 += bflo(h1.y); a3 += bfhi(h1.y);
        a4 += bflo(h1.z); a5 += bfhi(h1.z);
        a6 += bflo(h1.w); a7 += bfhi(h1.w);
    }
    if (e < e1) {
        int s0 = csr_src[e];
        uint4 h0 = Hb[s0 * 16 + p];
        a0 += bflo(h0.x); a1 += bfhi(h0.x);
        a2 += bflo(h0.y); a3 += bfhi(h0.y);
        a4 += bflo(h0.z); a5 += bfhi(h0.z);
        a6 += bflo(h0.w); a7 += bfhi(h0.w);
    }
#pragma unroll
    for (int m = 16; m <= 32; m <<= 1) {
        a0 += __shfl_xor(a0, m); a1 += __shfl_xor(a1, m);
        a2 += __shfl_xor(a2, m); a3 += __shfl_xor(a3, m);
        a4 += __shfl_xor(a4, m); a5 += __shfl_xor(a5, m);
        a6 += __shfl_xor(a6, m); a7 += __shfl_xor(a7, m);
    }
    float dd = dis[node];
    int c0 = p * 8 + g * 2;
    float x = (g == 0) ? a0 : (g == 1) ? a2 : (g == 2) ? a4 : a6;
    float y = (g == 0) ? a1 : (g == 1) ? a3 : (g == 2) ? a5 : a7;
    float2 b2 = *(const float2*)&bias[c0];
    float2 o = { fmaf(x, dd, b2.x), fmaf(y, dd, b2.y) };
    *(float2*)&out[(long)node * 128 + c0] = o;
}

// ---------------- BatchNorm stats: per-block partials (no atomics) ----------------
__global__ void k_bnstats(const float* __restrict__ X, float* __restrict__ part,
                          int rowsPerBlock) {
    __shared__ float ls[256], ls2[256];
    int t = threadIdx.x;
    int col = t & 127, half = t >> 7;
    int r0 = blockIdx.x * rowsPerBlock;
    int r1 = r0 + rowsPerBlock; if (r1 > NN) r1 = NN;
    float s = 0.f, s2 = 0.f;
    for (int r = r0 + half; r < r1; r += 2) {
        float v = X[(long)r * 128 + col];
        s += v; s2 += v * v;
    }
    ls[t] = s; ls2[t] = s2;
    __syncthreads();
    if (t < 128) {
        part[blockIdx.x * 256 + t]       = ls[t]  + ls[t + 128];
        part[blockIdx.x * 256 + 128 + t] = ls2[t] + ls2[t + 128];
    }
}

__global__ void k_bnfinal(const float* __restrict__ part, const float* __restrict__ g,
                          const float* __restrict__ b, float* __restrict__ ss) {
    __shared__ float acc[512];
    int t = threadIdx.x;           // 256
    int c = t & 127, half = t >> 7;
    float s = 0.f, s2 = 0.f;
    for (int bb = half; bb < STATB; bb += 2) {
        s  += part[bb * 256 + c];
        s2 += part[bb * 256 + 128 + c];
    }
    acc[t] = s; acc[256 + t] = s2;
    __syncthreads();
    if (t < 128) {
        float S  = acc[t] + acc[t + 128];
        float S2 = acc[256 + t] + acc[256 + t + 128];
        float mean = S * (1.0f / NN);
        float var  = S2 * (1.0f / NN) - mean * mean;
        float scale = g[t] * rsqrtf(var + BNEPS);
        ss[t] = scale;
        ss[128 + t] = b[t] - mean * scale;
    }
}

// ---------------- fused BN2+ReLU + emb write + attention scores ----------------
__global__ __launch_bounds__(256, 2)
void k_scores(const float* __restrict__ X, const float* __restrict__ ss,
              float* __restrict__ emb,
              const float* __restrict__ w1, const float* __restrict__ b1,
              const float* __restrict__ w2, const float* __restrict__ b2,
              float* __restrict__ scores) {
    __shared__ float4 xs[64 * 32];  // 32 KB
    int t = threadIdx.x;
    long rowbase = (long)blockIdx.x * 64;
    const float4* Xv = (const float4*)(X + rowbase * 128);
    float4* Ev = (float4*)(emb + rowbase * 128);
#pragma unroll
    for (int i = 0; i < 8; ++i) {
        int f = t + 256 * i;
        int c4 = (f & 31) * 4;
        float4 v = Xv[f];
        float4 sc = *(const float4*)&ss[c4];
        float4 sh = *(const float4*)&ss[128 + c4];
        v.x = fmaxf(fmaf(v.x, sc.x, sh.x), 0.f);
        v.y = fmaxf(fmaf(v.y, sc.y, sh.y), 0.f);
        v.z = fmaxf(fmaf(v.z, sc.z, sh.z), 0.f);
        v.w = fmaxf(fmaf(v.w, sc.w, sh.w), 0.f);
        Ev[f] = v;
        xs[f] = v;
    }
    __syncthreads();

    int cg = t & 15;            // col group: cols cg*4 .. +3 (of 64)
    int r0 = (t >> 4) * 4;      // 4 rows
    const float4* Wv = (const float4*)w1;
    float4 bb = ((const float4*)b1)[cg];

    float4 acc[4];
#pragma unroll
    for (int i = 0; i < 4; ++i) acc[i] = bb;

    for (int k4 = 0; k4 < 32; ++k4) {
        float4 w0 = Wv[(4 * k4 + 0) * 16 + cg];
        float4 w1v = Wv[(4 * k4 + 1) * 16 + cg];
        float4 w2v = Wv[(4 * k4 + 2) * 16 + cg];
        float4 w3 = Wv[(4 * k4 + 3) * 16 + cg];
#pragma unroll
        for (int i = 0; i < 4; ++i) {
            float4 xv = xs[(r0 + i) * 32 + k4];
            acc[i].x = fmaf(xv.x, w0.x, acc[i].x);
            acc[i].x = fmaf(xv.y, w1v.x, acc[i].x);
            acc[i].x = fmaf(xv.z, w2v.x, acc[i].x);
            acc[i].x = fmaf(xv.w, w3.x, acc[i].x);
            acc[i].y = fmaf(xv.x, w0.y, acc[i].y);
            acc[i].y = fmaf(xv.y, w1v.y, acc[i].y);
            acc[i].y = fmaf(xv.z, w2v.y, acc[i].y);
            acc[i].y = fmaf(xv.w, w3.y, acc[i].y);
            acc[i].z = fmaf(xv.x, w0.z, acc[i].z);
            acc[i].z = fmaf(xv.y, w1v.z, acc[i].z);
            acc[i].z = fmaf(xv.z, w2v.z, acc[i].z);
            acc[i].z = fmaf(xv.w, w3.z, acc[i].z);
            acc[i].w = fmaf(xv.x, w0.w, acc[i].w);
            acc[i].w = fmaf(xv.y, w1v.w, acc[i].w);
            acc[i].w = fmaf(xv.z, w2v.w, acc[i].w);
            acc[i].w = fmaf(xv.w, w3.w, acc[i].w);
        }
    }
    float4 w2v = ((const float4*)w2)[cg];
    float b2v = b2[0];
#pragma unroll
    for (int i = 0; i < 4; ++i) {
        float v = tanhf(acc[i].x) * w2v.x + tanhf(acc[i].y) * w2v.y
                + tanhf(acc[i].z) * w2v.z + tanhf(acc[i].w) * w2v.w;
        v += __shfl_xor(v, 1);
        v += __shfl_xor(v, 2);
        v += __shfl_xor(v, 4);
        v += __shfl_xor(v, 8);
        if (cg == 0) scores[rowbase + r0 + i] = v + b2v;
    }
}

// ---------------- softmax over genes within cell + weighted pool ----------------
__global__ void k_pool(const float* __restrict__ emb, const float* __restrict__ scores,
                       float* __restrict__ pooled) {
    __shared__ float sl[SUBG];
    __shared__ float red[512];
    int c = blockIdx.x;
    int t = threadIdx.x;   // 512 threads
    int base = c * SUBG;
    float lmax = -1e30f;
    for (int i = t; i < SUBG; i += 512) {
        float v = scores[base + i];
        sl[i] = v;
        lmax = fmaxf(lmax, v);
    }
    red[t] = lmax; __syncthreads();
    for (int off = 256; off > 0; off >>= 1) {
        if (t < off) red[t] = fmaxf(red[t], red[t + off]);
        __syncthreads();
    }
    float mx = red[0]; __syncthreads();
    float lsum = 0.f;
    for (int i = t; i < SUBG; i += 512) {
        float e = __expf(sl[i] - mx);
        sl[i] = e;
        lsum += e;
    }
    red[t] = lsum; __syncthreads();
    for (int off = 256; off > 0; off >>= 1) {
        if (t < off) red[t] += red[t + off];
        __syncthreads();
    }
    float inv = 1.0f / red[0];
    __syncthreads();
    int col = t & 127, grp = t >> 7;   // 4 row-groups
    float acc = 0.f;
#pragma unroll 2
    for (int s = grp; s < SUBG; s += 4)
        acc += sl[s] * emb[(long)(base + s) * 128 + col];
    red[t] = acc; __syncthreads();
    if (grp == 0)
        pooled[c * 128 + col] = (red[col] + red[128 + col] + red[256 + col] + red[384 + col]) * inv;
}

// ---------------- dense head (parallel small kernels) ----------------
__global__ void k_head1(const float* __restrict__ pooled, const float* __restrict__ W,
                        const float* __restrict__ bias, float* __restrict__ Y) {
    __shared__ float row[128];
    int c = blockIdx.x, t = threadIdx.x;
    row[t] = pooled[c * 128 + t];
    __syncthreads();
    float acc = bias[t];
#pragma unroll 4
    for (int k = 0; k < 128; ++k) acc += row[k] * W[k * 128 + t];
    Y[c * 128 + t] = acc;
}

__global__ void k_headbn(const float* __restrict__ X, const float* __restrict__ g,
                         const float* __restrict__ b, float* __restrict__ Y, int cols) {
    int t = threadIdx.x;
    if (t >= cols) return;
    float s = 0.f, s2 = 0.f;
    for (int r = 0; r < CELLS; ++r) {
        float v = X[r * cols + t];
        s += v; s2 += v * v;
    }
    float mean = s * (1.0f / CELLS);
    float var = s2 * (1.0f / CELLS) - mean * mean;
    float scale = g[t] * rsqrtf(var + BNEPS);
    float shift = b[t] - mean * scale;
    for (int r = 0; r < CELLS; ++r)
        Y[r * cols + t] = fmaxf(X[r * cols + t] * scale + shift, 0.f);
}

__global__ void k_head2(const float* __restrict__ Y1, const float* __restrict__ W,
                        const float* __restrict__ bias, float* __restrict__ Y2) {
    __shared__ float row[128];
    int c = blockIdx.x, t = threadIdx.x;   // 128 threads
    row[t] = Y1[c * 128 + t];
    __syncthreads();
    if (t < 32) {
        float acc = bias[t];
#pragma unroll 4
        for (int k = 0; k < 128; ++k) acc += row[k] * W[k * 32 + t];
        Y2[c * 32 + t] = acc;
    }
}

// ---------------- launcher ----------------
extern "C" void kernel_launch(void* const* d_in, const int* in_sizes, int n_in,
                              void* d_out, int out_size, void* d_ws, size_t ws_size,
                              hipStream_t stream) {
    const float* x        = (const float*)d_in[0];
    const int*   ei       = (const int*)d_in[1];
    const float* conv1_w  = (const float*)d_in[2];
    const float* conv1_b  = (const float*)d_in[3];
    const float* bn1_g    = (const float*)d_in[4];
    const float* bn1_b    = (const float*)d_in[5];
    const float* conv2_w  = (const float*)d_in[6];
    const float* conv2_b  = (const float*)d_in[7];
    const float* bn2_g    = (const float*)d_in[8];
    const float* bn2_b    = (const float*)d_in[9];
    const float* att_w1   = (const float*)d_in[10];
    const float* att_b1   = (const float*)d_in[11];
    const float* att_w2   = (const float*)d_in[12];
    const float* att_b2   = (const float*)d_in[13];
    const float* fc_w     = (const float*)d_in[14];
    const float* fc_b     = (const float*)d_in[15];
    const float* bne_g    = (const float*)d_in[16];
    const float* bne_b    = (const float*)d_in[17];
    const float* bot_w    = (const float*)d_in[18];
    const float* bot_b    = (const float*)d_in[19];
    const float* bnb_g    = (const float*)d_in[20];
    const float* bnb_b    = (const float*)d_in[21];

    const int* src = ei;
    const int* dst = ei + EE;

    float* y_out   = (float*)d_out;            // [100,32]
    float* emb_out = y_out + CELLS * 32;       // [40000,128]

    float* ws = (float*)d_ws;
    float* F1     = ws;                              // N*H f32 (20.5 MB)
    u32*   Hb     = (u32*)(ws + (long)NN * HD);      // N*64 u32 (bf16 H', 10.25 MB)
    float* fbase  = ws + (long)NN * HD + (long)NN * 64;
    float* dis    = fbase;                     // N
    float* scores = dis + NN;                  // N
    float* part   = scores + NN;               // STATB*256
    float* sstats = part + STATB * 256;        // 256
    float* pooled = sstats + 256;              // C*H
    float* y1pre  = pooled + CELLS * HD;       // C*H
    float* y1     = y1pre + CELLS * HD;        // C*H
    float* y2pre  = y1 + CELLS * HD;           // C*32
    int* ibase    = (int*)(y2pre + CELLS * 32);
    int* deg      = ibase;                     // N
    int* cursor   = deg + NN;                  // N
    int* excl     = cursor + NN;               // N
    int* rowstart = excl + NN;                 // N+1
    int* partsc   = rowstart + NN + 1;         // NPB
    int* partx    = partsc + NPB;              // NPB
    int* csr_src  = partx + NPB;               // E

    // ---- CSR build (shared by both convs) ----
    k_zeroi<<<(2 * NN + 255) / 256, 256, 0, stream>>>(deg, 2 * NN);
    k_degcount<<<1024, 256, 0, stream>>>(dst, deg);
    k_scan1<<<NPB, 256, 0, stream>>>(deg, excl, partsc);
    k_scan2<<<1, 256, 0, stream>>>(partsc, partx);
    k_scan3<<<NPB, 256, 0, stream>>>(excl, partx, deg, rowstart, dis);
    k_fill<<<2048, 256, 0, stream>>>(src, dst, rowstart, cursor, csr_src);

    // ---- conv1 ----
    k_gemm128<<<625, 256, 0, stream>>>(x, conv1_w, Hb, nullptr, dis);
    k_gather<<<10000, 256, 0, stream>>>((const uint4*)Hb, rowstart, csr_src, dis, conv1_b, F1);
    k_bnstats<<<STATB, 256, 0, stream>>>(F1, part, 250);
    k_bnfinal<<<1, 256, 0, stream>>>(part, bn1_g, bn1_b, sstats);

    // ---- conv2 (BN1+ReLU fused into GEMM staging) ----
    k_gemm128<<<625, 256, 0, stream>>>(F1, conv2_w, Hb, sstats, dis);
    k_gather<<<10000, 256, 0, stream>>>((const uint4*)Hb, rowstart, csr_src, dis, conv2_b, F1);
    k_bnstats<<<STATB, 256, 0, stream>>>(F1, part, 250);
    k_bnfinal<<<1, 256, 0, stream>>>(part, bn2_g, bn2_b, sstats);

    // ---- BN2+ReLU + emb write + attention scores (fused) ----
    k_scores<<<625, 256, 0, stream>>>(F1, sstats, emb_out, att_w1, att_b1, att_w2, att_b2, scores);
    k_pool<<<CELLS, 512, 0, stream>>>(emb_out, scores, pooled);

    // ---- head (parallel small kernels) ----
    k_head1<<<CELLS, 128, 0, stream>>>(pooled, fc_w, fc_b, y1pre);
    k_headbn<<<1, 128, 0, stream>>>(y1pre, bne_g, bne_b, y1, 128);
    k_head2<<<CELLS, 128, 0, stream>>>(y1, bot_w, bot_b, y2pre);
    k_headbn<<<1, 64, 0, stream>>>(y2pre, bnb_g, bnb_b, y_out, 32);
}

// Round 8
// 351.808 us; speedup vs baseline: 1.1230x; 1.0330x over previous
//
#include <hip/hip_runtime.h>
#include <math.h>

typedef unsigned int u32;
typedef __attribute__((ext_vector_type(8))) short bf16x8;
typedef __attribute__((ext_vector_type(4))) float f32x4;

#define NN   40000
#define EE   640000
#define FD   128
#define HD   128
#define SUBG 400
#define CELLS 100
#define BNEPS 1e-5f
#define NPB  157   // ceil(NN/256)
#define STATB 160  // bnstats blocks

// ---- bf16 helpers (pack with RNE, unpack via bit-shift) ----
__device__ __forceinline__ u32 bf16pair(float a, float b) {
    u32 ua = __float_as_uint(a), ub = __float_as_uint(b);
    ua += 0x7fffu + ((ua >> 16) & 1u);
    ub += 0x7fffu + ((ub >> 16) & 1u);
    return (ua >> 16) | (ub & 0xffff0000u);
}
__device__ __forceinline__ float bflo(u32 u) { return __uint_as_float(u << 16); }
__device__ __forceinline__ float bfhi(u32 u) { return __uint_as_float(u & 0xffff0000u); }

// ---------------- CSR build ----------------
__global__ void k_zeroi(int* p, int n) {
    int i = blockIdx.x * blockDim.x + threadIdx.x;
    if (i < n) p[i] = 0;
}

__global__ void k_degcount(const int* __restrict__ dst, int* __restrict__ deg) {
    int i = blockIdx.x * blockDim.x + threadIdx.x;
    int stride = gridDim.x * blockDim.x;
    for (; i < EE; i += stride) atomicAdd(&deg[dst[i]], 1);
}

__global__ void k_scan1(const int* __restrict__ deg, int* __restrict__ excl,
                        int* __restrict__ part) {
    __shared__ int s[256];
    int t = threadIdx.x;
    int i = blockIdx.x * 256 + t;
    int v = (i < NN) ? deg[i] : 0;
    s[t] = v;
    __syncthreads();
    for (int off = 1; off < 256; off <<= 1) {
        int add = (t >= off) ? s[t - off] : 0;
        __syncthreads();
        s[t] += add;
        __syncthreads();
    }
    if (i < NN) excl[i] = s[t] - v;
    if (t == 255) part[blockIdx.x] = s[255];
}

__global__ void k_scan2(int* __restrict__ part, int* __restrict__ partx) {
    __shared__ int s[256];
    int t = threadIdx.x;
    int v = (t < NPB) ? part[t] : 0;
    s[t] = v;
    __syncthreads();
    for (int off = 1; off < 256; off <<= 1) {
        int add = (t >= off) ? s[t - off] : 0;
        __syncthreads();
        s[t] += add;
        __syncthreads();
    }
    if (t < NPB) partx[t] = s[t] - v;
}

__global__ void k_scan3(const int* __restrict__ excl, const int* __restrict__ partx,
                        const int* __restrict__ deg, int* __restrict__ rowstart,
                        float* __restrict__ dis) {
    int i = blockIdx.x * 256 + threadIdx.x;
    if (i < NN) {
        rowstart[i] = excl[i] + partx[blockIdx.x];
        dis[i] = rsqrtf((float)(deg[i] + 1));   // +1 self-loop
    }
    if (i == 0) rowstart[NN] = EE;
}

__global__ void k_fill(const int* __restrict__ src, const int* __restrict__ dst,
                       const int* __restrict__ rowstart, int* __restrict__ cursor,
                       int* __restrict__ csr_src) {
    int i = blockIdx.x * blockDim.x + threadIdx.x;
    int stride = gridDim.x * blockDim.x;
    for (; i < EE; i += stride) {
        int d = dst[i];
        int slot = rowstart[d] + atomicAdd(&cursor[d], 1);
        csr_src[slot] = src[i];
    }
}

// ---------------- weight prep: Wt[n][k] bf16-packed, both conv weights ----------------
// Wt u32 layout: Wt[n*64 + k/2] = pack(W[k][n], W[k+1][n])
__global__ void k_wprep(const float* __restrict__ W1, u32* __restrict__ Wt1,
                        const float* __restrict__ W2, u32* __restrict__ Wt2) {
    int i = blockIdx.x * 256 + threadIdx.x;   // 64 blocks: 0..8191 -> W1, 8192..16383 -> W2
    const float* W = (i < 8192) ? W1 : W2;
    u32* Wt = (i < 8192) ? Wt1 : Wt2;
    int j = i & 8191;
    int n = j >> 6, k2 = (j & 63) * 2;
    float lo = W[k2 * 128 + n];
    float hi = W[(k2 + 1) * 128 + n];
    Wt[n * 64 + (j & 63)] = bf16pair(lo, hi);
}

// ---------------- MFMA GEMM  Yb[M,128](bf16) = dis[r] * (X[M,128] @ W) ----------------
// Block = 4 waves, each wave: 16 rows x 128 cols, K=128 one-shot.
// A: direct global reads + optional BN/ReLU + bf16 convert in regs.
// B: Wt[n][k] bf16 from global (L2-broadcast).
// Frag layout (m91/m97 convention): A/B lane holds 8 contiguous k at m/n=lane&15,
// k-block=lane>>4; D: col=lane&15, row=(lane>>4)*4+reg.
__global__ __launch_bounds__(256)
void k_gemm_mfma(const float* __restrict__ X, const u32* __restrict__ Wt,
                 u32* __restrict__ Yb, const float* __restrict__ ss,
                 const float* __restrict__ dis) {
    int t = threadIdx.x;
    int l = t & 63, wv = t >> 6;
    int rowbase = blockIdx.x * 64 + wv * 16;
    int ml = l & 15;            // A row / B col within tile
    int kg = l >> 4;            // k-group 0..3

    f32x4 acc[8];
#pragma unroll
    for (int nt = 0; nt < 8; ++nt) acc[nt] = (f32x4){0.f, 0.f, 0.f, 0.f};

    const float* xr = X + (long)(rowbase + ml) * 128;

#pragma unroll
    for (int kk = 0; kk < 4; ++kk) {
        int k0 = kk * 32 + kg * 8;
        float4 xa = *(const float4*)&xr[k0];
        float4 xb = *(const float4*)&xr[k0 + 4];
        if (ss) {
            float4 sca = *(const float4*)&ss[k0];
            float4 sha = *(const float4*)&ss[128 + k0];
            float4 scb = *(const float4*)&ss[k0 + 4];
            float4 shb = *(const float4*)&ss[128 + k0 + 4];
            xa.x = fmaxf(fmaf(xa.x, sca.x, sha.x), 0.f);
            xa.y = fmaxf(fmaf(xa.y, sca.y, sha.y), 0.f);
            xa.z = fmaxf(fmaf(xa.z, sca.z, sha.z), 0.f);
            xa.w = fmaxf(fmaf(xa.w, sca.w, sha.w), 0.f);
            xb.x = fmaxf(fmaf(xb.x, scb.x, shb.x), 0.f);
            xb.y = fmaxf(fmaf(xb.y, scb.y, shb.y), 0.f);
            xb.z = fmaxf(fmaf(xb.z, scb.z, shb.z), 0.f);
            xb.w = fmaxf(fmaf(xb.w, scb.w, shb.w), 0.f);
        }
        union { u32 u[4]; bf16x8 v; } af;
        af.u[0] = bf16pair(xa.x, xa.y);
        af.u[1] = bf16pair(xa.z, xa.w);
        af.u[2] = bf16pair(xb.x, xb.y);
        af.u[3] = bf16pair(xb.z, xb.w);
#pragma unroll
        for (int nt = 0; nt < 8; ++nt) {
            bf16x8 b = *(const bf16x8*)&Wt[(nt * 16 + ml) * 64 + (k0 >> 1)];
            acc[nt] = __builtin_amdgcn_mfma_f32_16x16x32_bf16(af.v, b, acc[nt], 0, 0, 0);
        }
    }

    // epilogue: dis-prescale, pair-pack bf16, even lanes store u32
#pragma unroll
    for (int r = 0; r < 4; ++r) {
        int m = rowbase + kg * 4 + r;
        float dd = dis[m];
        long base = (long)m * 64;
#pragma unroll
        for (int nt = 0; nt < 8; ++nt) {
            float v = acc[nt][r] * dd;
            float v2 = __shfl_xor(v, 1);
            if ((l & 1) == 0)
                Yb[base + nt * 8 + (ml >> 1)] = bf16pair(v, v2);
        }
    }
}

// ---------------- GCN aggregation: bf16 CSR gather over pre-scaled rows ----------------
__global__ void k_gather(const uint4* __restrict__ Hb, const int* __restrict__ rowstart,
                         const int* __restrict__ csr_src, const float* __restrict__ dis,
                         const float* __restrict__ bias, float* __restrict__ out) {
    int lane = threadIdx.x & 63;
    int node = (blockIdx.x * blockDim.x + threadIdx.x) >> 6;
    if (node >= NN) return;
    int g = lane >> 4, p = lane & 15;
    float a0 = 0.f, a1 = 0.f, a2 = 0.f, a3 = 0.f, a4 = 0.f, a5 = 0.f, a6 = 0.f, a7 = 0.f;
    if (g == 0) {   // self-loop term, counted once
        uint4 h = Hb[node * 16 + p];
        a0 = bflo(h.x); a1 = bfhi(h.x);
        a2 = bflo(h.y); a3 = bfhi(h.y);
        a4 = bflo(h.z); a5 = bfhi(h.z);
        a6 = bflo(h.w); a7 = bfhi(h.w);
    }
    int e1 = rowstart[node + 1];
    int e = rowstart[node] + g;
    for (; e + 4 < e1; e += 8) {
        int s0 = csr_src[e];
        int s1 = csr_src[e + 4];
        uint4 h0 = Hb[s0 * 16 + p];
        uint4 h1 = Hb[s1 * 16 + p];
        a0 += bflo(h0.x); a1 += bfhi(h0.x);
        a2 += bflo(h0.y); a3 += bfhi(h0.y);
        a4 += bflo(h0.z); a5 += bfhi(h0.z);
        a6 += bflo(h0.w); a7 += bfhi(h0.w);
        a0 += bflo(h1.x); a1 += bfhi(h1.x);
        a2 += bflo(h1.y); a3 += bfhi(h1.y);
        a4 += bflo(h1.z); a5 += bfhi(h1.z);
        a6 += bflo(h1.w); a7 += bfhi(h1.w);
    }
    if (e < e1) {
        int s0 = csr_src[e];
        uint4 h0 = Hb[s0 * 16 + p];
        a0 += bflo(h0.x); a1 += bfhi(h0.x);
        a2 += bflo(h0.y); a3 += bfhi(h0.y);
        a4 += bflo(h0.z); a5 += bfhi(h0.z);
        a6 += bflo(h0.w); a7 += bfhi(h0.w);
    }
#pragma unroll
    for (int m = 16; m <= 32; m <<= 1) {
        a0 += __shfl_xor(a0, m); a1 += __shfl_xor(a1, m);
        a2 += __shfl_xor(a2, m); a3 += __shfl_xor(a3, m);
        a4 += __shfl_xor(a4, m); a5 += __shfl_xor(a5, m);
        a6 += __shfl_xor(a6, m); a7 += __shfl_xor(a7, m);
    }
    float dd = dis[node];
    int c0 = p * 8 + g * 2;
    float x = (g == 0) ? a0 : (g == 1) ? a2 : (g == 2) ? a4 : a6;
    float y = (g == 0) ? a1 : (g == 1) ? a3 : (g == 2) ? a5 : a7;
    float2 b2 = *(const float2*)&bias[c0];
    float2 o = { fmaf(x, dd, b2.x), fmaf(y, dd, b2.y) };
    *(float2*)&out[(long)node * 128 + c0] = o;
}

// ---------------- BatchNorm stats: per-block partials (no atomics) ----------------
__global__ void k_bnstats(const float* __restrict__ X, float* __restrict__ part,
                          int rowsPerBlock) {
    __shared__ float ls[256], ls2[256];
    int t = threadIdx.x;
    int col = t & 127, half = t >> 7;
    int r0 = blockIdx.x * rowsPerBlock;
    int r1 = r0 + rowsPerBlock; if (r1 > NN) r1 = NN;
    float s = 0.f, s2 = 0.f;
    for (int r = r0 + half; r < r1; r += 2) {
        float v = X[(long)r * 128 + col];
        s += v; s2 += v * v;
    }
    ls[t] = s; ls2[t] = s2;
    __syncthreads();
    if (t < 128) {
        part[blockIdx.x * 256 + t]       = ls[t]  + ls[t + 128];
        part[blockIdx.x * 256 + 128 + t] = ls2[t] + ls2[t + 128];
    }
}

__global__ void k_bnfinal(const float* __restrict__ part, const float* __restrict__ g,
                          const float* __restrict__ b, float* __restrict__ ss) {
    __shared__ float acc[512];
    int t = threadIdx.x;           // 256
    int c = t & 127, half = t >> 7;
    float s = 0.f, s2 = 0.f;
    for (int bb = half; bb < STATB; bb += 2) {
        s  += part[bb * 256 + c];
        s2 += part[bb * 256 + 128 + c];
    }
    acc[t] = s; acc[256 + t] = s2;
    __syncthreads();
    if (t < 128) {
        float S  = acc[t] + acc[t + 128];
        float S2 = acc[256 + t] + acc[256 + t + 128];
        float mean = S * (1.0f / NN);
        float var  = S2 * (1.0f / NN) - mean * mean;
        float scale = g[t] * rsqrtf(var + BNEPS);
        ss[t] = scale;
        ss[128 + t] = b[t] - mean * scale;
    }
}

// ---------------- fused BN2+ReLU + emb write + attention scores ----------------
__global__ __launch_bounds__(256, 2)
void k_scores(const float* __restrict__ X, const float* __restrict__ ss,
              float* __restrict__ emb,
              const float* __restrict__ w1, const float* __restrict__ b1,
              const float* __restrict__ w2, const float* __restrict__ b2,
              float* __restrict__ scores) {
    __shared__ float4 xs[64 * 32];  // 32 KB
    int t = threadIdx.x;
    long rowbase = (long)blockIdx.x * 64;
    const float4* Xv = (const float4*)(X + rowbase * 128);
    float4* Ev = (float4*)(emb + rowbase * 128);
#pragma unroll
    for (int i = 0; i < 8; ++i) {
        int f = t + 256 * i;
        int c4 = (f & 31) * 4;
        float4 v = Xv[f];
        float4 sc = *(const float4*)&ss[c4];
        float4 sh = *(const float4*)&ss[128 + c4];
        v.x = fmaxf(fmaf(v.x, sc.x, sh.x), 0.f);
        v.y = fmaxf(fmaf(v.y, sc.y, sh.y), 0.f);
        v.z = fmaxf(fmaf(v.z, sc.z, sh.z), 0.f);
        v.w = fmaxf(fmaf(v.w, sc.w, sh.w), 0.f);
        Ev[f] = v;
        xs[f] = v;
    }
    __syncthreads();

    int cg = t & 15;            // col group: cols cg*4 .. +3 (of 64)
    int r0 = (t >> 4) * 4;      // 4 rows
    const float4* Wv = (const float4*)w1;
    float4 bb = ((const float4*)b1)[cg];

    float4 acc[4];
#pragma unroll
    for (int i = 0; i < 4; ++i) acc[i] = bb;

    for (int k4 = 0; k4 < 32; ++k4) {
        float4 w0 = Wv[(4 * k4 + 0) * 16 + cg];
        float4 w1v = Wv[(4 * k4 + 1) * 16 + cg];
        float4 w2v = Wv[(4 * k4 + 2) * 16 + cg];
        float4 w3 = Wv[(4 * k4 + 3) * 16 + cg];
#pragma unroll
        for (int i = 0; i < 4; ++i) {
            float4 xv = xs[(r0 + i) * 32 + k4];
            acc[i].x = fmaf(xv.x, w0.x, acc[i].x);
            acc[i].x = fmaf(xv.y, w1v.x, acc[i].x);
            acc[i].x = fmaf(xv.z, w2v.x, acc[i].x);
            acc[i].x = fmaf(xv.w, w3.x, acc[i].x);
            acc[i].y = fmaf(xv.x, w0.y, acc[i].y);
            acc[i].y = fmaf(xv.y, w1v.y, acc[i].y);
            acc[i].y = fmaf(xv.z, w2v.y, acc[i].y);
            acc[i].y = fmaf(xv.w, w3.y, acc[i].y);
            acc[i].z = fmaf(xv.x, w0.z, acc[i].z);
            acc[i].z = fmaf(xv.y, w1v.z, acc[i].z);
            acc[i].z = fmaf(xv.z, w2v.z, acc[i].z);
            acc[i].z = fmaf(xv.w, w3.z, acc[i].z);
            acc[i].w = fmaf(xv.x, w0.w, acc[i].w);
            acc[i].w = fmaf(xv.y, w1v.w, acc[i].w);
            acc[i].w = fmaf(xv.z, w2v.w, acc[i].w);
            acc[i].w = fmaf(xv.w, w3.w, acc[i].w);
        }
    }
    float4 w2v = ((const float4*)w2)[cg];
    float b2v = b2[0];
#pragma unroll
    for (int i = 0; i < 4; ++i) {
        float v = tanhf(acc[i].x) * w2v.x + tanhf(acc[i].y) * w2v.y
                + tanhf(acc[i].z) * w2v.z + tanhf(acc[i].w) * w2v.w;
        v += __shfl_xor(v, 1);
        v += __shfl_xor(v, 2);
        v += __shfl_xor(v, 4);
        v += __shfl_xor(v, 8);
        if (cg == 0) scores[rowbase + r0 + i] = v + b2v;
    }
}

// ---------------- softmax over genes within cell + weighted pool ----------------
__global__ void k_pool(const float* __restrict__ emb, const float* __restrict__ scores,
                       float* __restrict__ pooled) {
    __shared__ float sl[SUBG];
    __shared__ float red[512];
    int c = blockIdx.x;
    int t = threadIdx.x;   // 512 threads
    int base = c * SUBG;
    float lmax = -1e30f;
    for (int i = t; i < SUBG; i += 512) {
        float v = scores[base + i];
        sl[i] = v;
        lmax = fmaxf(lmax, v);
    }
    red[t] = lmax; __syncthreads();
    for (int off = 256; off > 0; off >>= 1) {
        if (t < off) red[t] = fmaxf(red[t], red[t + off]);
        __syncthreads();
    }
    float mx = red[0]; __syncthreads();
    float lsum = 0.f;
    for (int i = t; i < SUBG; i += 512) {
        float e = __expf(sl[i] - mx);
        sl[i] = e;
        lsum += e;
    }
    red[t] = lsum; __syncthreads();
    for (int off = 256; off > 0; off >>= 1) {
        if (t < off) red[t] += red[t + off];
        __syncthreads();
    }
    float inv = 1.0f / red[0];
    __syncthreads();
    int col = t & 127, grp = t >> 7;   // 4 row-groups
    float acc = 0.f;
#pragma unroll 2
    for (int s = grp; s < SUBG; s += 4)
        acc += sl[s] * emb[(long)(base + s) * 128 + col];
    red[t] = acc; __syncthreads();
    if (grp == 0)
        pooled[c * 128 + col] = (red[col] + red[128 + col] + red[256 + col] + red[384 + col]) * inv;
}

// ---------------- dense head (parallel small kernels) ----------------
__global__ void k_head1(const float* __restrict__ pooled, const float* __restrict__ W,
                        const float* __restrict__ bias, float* __restrict__ Y) {
    __shared__ float row[128];
    int c = blockIdx.x, t = threadIdx.x;
    row[t] = pooled[c * 128 + t];
    __syncthreads();
    float acc = bias[t];
#pragma unroll 4
    for (int k = 0; k < 128; ++k) acc += row[k] * W[k * 128 + t];
    Y[c * 128 + t] = acc;
}

__global__ void k_headbn(const float* __restrict__ X, const float* __restrict__ g,
                         const float* __restrict__ b, float* __restrict__ Y, int cols) {
    int t = threadIdx.x;
    if (t >= cols) return;
    float s = 0.f, s2 = 0.f;
    for (int r = 0; r < CELLS; ++r) {
        float v = X[r * cols + t];
        s += v; s2 += v * v;
    }
    float mean = s * (1.0f / CELLS);
    float var = s2 * (1.0f / CELLS) - mean * mean;
    float scale = g[t] * rsqrtf(var + BNEPS);
    float shift = b[t] - mean * scale;
    for (int r = 0; r < CELLS; ++r)
        Y[r * cols + t] = fmaxf(X[r * cols + t] * scale + shift, 0.f);
}

__global__ void k_head2(const float* __restrict__ Y1, const float* __restrict__ W,
                        const float* __restrict__ bias, float* __restrict__ Y2) {
    __shared__ float row[128];
    int c = blockIdx.x, t = threadIdx.x;   // 128 threads
    row[t] = Y1[c * 128 + t];
    __syncthreads();
    if (t < 32) {
        float acc = bias[t];
#pragma unroll 4
        for (int k = 0; k < 128; ++k) acc += row[k] * W[k * 32 + t];
        Y2[c * 32 + t] = acc;
    }
}

// ---------------- launcher ----------------
extern "C" void kernel_launch(void* const* d_in, const int* in_sizes, int n_in,
                              void* d_out, int out_size, void* d_ws, size_t ws_size,
                              hipStream_t stream) {
    const float* x        = (const float*)d_in[0];
    const int*   ei       = (const int*)d_in[1];
    const float* conv1_w  = (const float*)d_in[2];
    const float* conv1_b  = (const float*)d_in[3];
    const float* bn1_g    = (const float*)d_in[4];
    const float* bn1_b    = (const float*)d_in[5];
    const float* conv2_w  = (const float*)d_in[6];
    const float* conv2_b  = (const float*)d_in[7];
    const float* bn2_g    = (const float*)d_in[8];
    const float* bn2_b    = (const float*)d_in[9];
    const float* att_w1   = (const float*)d_in[10];
    const float* att_b1   = (const float*)d_in[11];
    const float* att_w2   = (const float*)d_in[12];
    const float* att_b2   = (const float*)d_in[13];
    const float* fc_w     = (const float*)d_in[14];
    const float* fc_b     = (const float*)d_in[15];
    const float* bne_g    = (const float*)d_in[16];
    const float* bne_b    = (const float*)d_in[17];
    const float* bot_w    = (const float*)d_in[18];
    const float* bot_b    = (const float*)d_in[19];
    const float* bnb_g    = (const float*)d_in[20];
    const float* bnb_b    = (const float*)d_in[21];

    const int* src = ei;
    const int* dst = ei + EE;

    float* y_out   = (float*)d_out;            // [100,32]
    float* emb_out = y_out + CELLS * 32;       // [40000,128]

    float* ws = (float*)d_ws;
    float* F1     = ws;                              // N*H f32 (20.5 MB)
    u32*   Hb     = (u32*)(ws + (long)NN * HD);      // N*64 u32 (bf16 H', 10.25 MB)
    float* fbase  = ws + (long)NN * HD + (long)NN * 64;
    float* dis    = fbase;                     // N
    float* scores = dis + NN;                  // N
    float* part   = scores + NN;               // STATB*256
    float* sstats = part + STATB * 256;        // 256
    float* pooled = sstats + 256;              // C*H
    float* y1pre  = pooled + CELLS * HD;       // C*H
    float* y1     = y1pre + CELLS * HD;        // C*H
    float* y2pre  = y1 + CELLS * HD;           // C*32
    u32* Wt1      = (u32*)(y2pre + CELLS * 32);// 128*64 u32
    u32* Wt2      = Wt1 + 128 * 64;            // 128*64 u32
    int* ibase    = (int*)(Wt2 + 128 * 64);
    int* deg      = ibase;                     // N
    int* cursor   = deg + NN;                  // N
    int* excl     = cursor + NN;               // N
    int* rowstart = excl + NN;                 // N+1
    int* partsc   = rowstart + NN + 1;         // NPB
    int* partx    = partsc + NPB;              // NPB
    int* csr_src  = partx + NPB;               // E

    // ---- CSR build + weight prep ----
    k_zeroi<<<(2 * NN + 255) / 256, 256, 0, stream>>>(deg, 2 * NN);
    k_degcount<<<1024, 256, 0, stream>>>(dst, deg);
    k_wprep<<<64, 256, 0, stream>>>(conv1_w, Wt1, conv2_w, Wt2);
    k_scan1<<<NPB, 256, 0, stream>>>(deg, excl, partsc);
    k_scan2<<<1, 256, 0, stream>>>(partsc, partx);
    k_scan3<<<NPB, 256, 0, stream>>>(excl, partx, deg, rowstart, dis);
    k_fill<<<2048, 256, 0, stream>>>(src, dst, rowstart, cursor, csr_src);

    // ---- conv1 ----
    k_gemm_mfma<<<625, 256, 0, stream>>>(x, Wt1, Hb, nullptr, dis);
    k_gather<<<10000, 256, 0, stream>>>((const uint4*)Hb, rowstart, csr_src, dis, conv1_b, F1);
    k_bnstats<<<STATB, 256, 0, stream>>>(F1, part, 250);
    k_bnfinal<<<1, 256, 0, stream>>>(part, bn1_g, bn1_b, sstats);

    // ---- conv2 (BN1+ReLU fused into GEMM A-load) ----
    k_gemm_mfma<<<625, 256, 0, stream>>>(F1, Wt2, Hb, sstats, dis);
    k_gather<<<10000, 256, 0, stream>>>((const uint4*)Hb, rowstart, csr_src, dis, conv2_b, F1);
    k_bnstats<<<STATB, 256, 0, stream>>>(F1, part, 250);
    k_bnfinal<<<1, 256, 0, stream>>>(part, bn2_g, bn2_b, sstats);

    // ---- BN2+ReLU + emb write + attention scores (fused) ----
    k_scores<<<625, 256, 0, stream>>>(F1, sstats, emb_out, att_w1, att_b1, att_w2, att_b2, scores);
    k_pool<<<CELLS, 512, 0, stream>>>(emb_out, scores, pooled);

    // ---- head (parallel small kernels) ----
    k_head1<<<CELLS, 128, 0, stream>>>(pooled, fc_w, fc_b, y1pre);
    k_headbn<<<1, 128, 0, stream>>>(y1pre, bne_g, bne_b, y1, 128);
    k_head2<<<CELLS, 128, 0, stream>>>(y1, bot_w, bot_b, y2pre);
    k_headbn<<<1, 64, 0, stream>>>(y2pre, bnb_g, bnb_b, y_out, 32);
}

// Round 9
// 280.092 us; speedup vs baseline: 1.4105x; 1.2560x over previous
//
#include <hip/hip_runtime.h>
#include <math.h>

typedef unsigned int u32;
typedef __attribute__((ext_vector_type(8))) short bf16x8;
typedef __attribute__((ext_vector_type(4))) float f32x4;

#define NN   40000
#define EE   640000
#define SUBG 400
#define CELLS 100
#define BNEPS 1e-5f
#define GB   2048      // gather blocks (8192 waves = 32/CU)
#define GEMMB 625
#define FILLB 1024

// ---- bf16 helpers ----
__device__ __forceinline__ u32 bf16pair(float a, float b) {
    u32 ua = __float_as_uint(a), ub = __float_as_uint(b);
    ua += 0x7fffu + ((ua >> 16) & 1u);
    ub += 0x7fffu + ((ub >> 16) & 1u);
    return (ua >> 16) | (ub & 0xffff0000u);
}
__device__ __forceinline__ float bflo(u32 u) { return __uint_as_float(u << 16); }
__device__ __forceinline__ float bfhi(u32 u) { return __uint_as_float(u & 0xffff0000u); }

// LDS swizzle for k_cell tile: permute 16B chunks within a row keyed by row
#define SWZ(g, cc) ( ((cc) & 3) | (((((cc) >> 2) ^ ((g) & 15))) << 2) )

// ---------------- init: zero deg/cursor + bf16-transpose weights + zero head stats ----------------
__global__ void k_init(int* deg_cursor, const float* W1, u32* Wt1,
                       const float* W2, u32* Wt2, const float* wa, u32* Wta,
                       float* hstats) {
    int i = blockIdx.x * 256 + threadIdx.x;
    if (i < 2 * NN) { deg_cursor[i] = 0; return; }
    i -= 2 * NN;
    if (i < 16384) {
        const float* W = (i < 8192) ? W1 : W2;
        u32* Wt = (i < 8192) ? Wt1 : Wt2;
        int j = i & 8191;
        int n = j >> 6, k2 = (j & 63) * 2;
        Wt[n * 64 + (j & 63)] = bf16pair(W[k2 * 128 + n], W[(k2 + 1) * 128 + n]);
        return;
    }
    i -= 16384;
    if (i < 4096) {
        int n = i >> 6, k2 = (i & 63) * 2;
        Wta[n * 64 + (i & 63)] = bf16pair(wa[k2 * 64 + n], wa[(k2 + 1) * 64 + n]);
        return;
    }
    i -= 4096;
    if (i < 320) hstats[i] = 0.f;
}

// ---------------- degree count ----------------
__global__ void k_degcount(const int* __restrict__ dst, int* __restrict__ deg) {
    int i = blockIdx.x * blockDim.x + threadIdx.x;
    int stride = gridDim.x * blockDim.x;
    for (; i < EE; i += stride) atomicAdd(&deg[dst[i]], 1);
}

// ---------------- single-block full exclusive scan + dis ----------------
__global__ __launch_bounds__(1024)
void k_scan(const int* __restrict__ deg, int* __restrict__ rowstart,
            float* __restrict__ dis) {
    __shared__ int ps[1024];
    int t = threadIdx.x;
    int base = t * 40;
    int ld[40];
    int lsum = 0;
#pragma unroll
    for (int j = 0; j < 40; ++j) {
        int idx = base + j;
        int v = (idx < NN) ? deg[idx] : 0;
        ld[j] = v; lsum += v;
    }
    ps[t] = lsum;
    __syncthreads();
    for (int off = 1; off < 1024; off <<= 1) {
        int add = (t >= off) ? ps[t - off] : 0;
        __syncthreads();
        ps[t] += add;
        __syncthreads();
    }
    int run = ps[t] - lsum;
#pragma unroll
    for (int j = 0; j < 40; ++j) {
        int idx = base + j;
        if (idx < NN) {
            rowstart[idx] = run;
            dis[idx] = rsqrtf((float)(ld[j] + 1));
            run += ld[j];
        }
    }
    if (t == 0) rowstart[NN] = EE;
}

// ---------------- fill CSR  ||  conv1 MFMA GEMM (merged dispatch) ----------------
// blocks [0,GEMMB): Yb = bf16(dis[r] * X@W)   (f32 input, no BN)
// blocks [GEMMB, GEMMB+FILLB): CSR slot fill
__global__ __launch_bounds__(256)
void k_fillgemm(const float* __restrict__ X, const u32* __restrict__ Wt,
                u32* __restrict__ Yb, const float* __restrict__ dis,
                const int* __restrict__ src, const int* __restrict__ dst,
                const int* __restrict__ rowstart, int* __restrict__ cursor,
                int* __restrict__ csr_src) {
    int bid = blockIdx.x;
    int t = threadIdx.x;
    if (bid >= GEMMB) {
        int i = (bid - GEMMB) * 256 + t;
        int stride = FILLB * 256;
        for (; i < EE; i += stride) {
            int d = dst[i];
            int slot = rowstart[d] + atomicAdd(&cursor[d], 1);
            csr_src[slot] = src[i];
        }
        return;
    }
    int l = t & 63, wv = t >> 6;
    int rowbase = bid * 64 + wv * 16;
    int ml = l & 15, kg = l >> 4;

    f32x4 acc[8];
#pragma unroll
    for (int nt = 0; nt < 8; ++nt) acc[nt] = (f32x4){0.f, 0.f, 0.f, 0.f};
    const float* xr = X + (long)(rowbase + ml) * 128;
#pragma unroll
    for (int kk = 0; kk < 4; ++kk) {
        int k0 = kk * 32 + kg * 8;
        float4 xa = *(const float4*)&xr[k0];
        float4 xb = *(const float4*)&xr[k0 + 4];
        union { u32 u[4]; bf16x8 v; } af;
        af.u[0] = bf16pair(xa.x, xa.y);
        af.u[1] = bf16pair(xa.z, xa.w);
        af.u[2] = bf16pair(xb.x, xb.y);
        af.u[3] = bf16pair(xb.z, xb.w);
#pragma unroll
        for (int nt = 0; nt < 8; ++nt) {
            bf16x8 b = *(const bf16x8*)&Wt[(nt * 16 + ml) * 64 + (k0 >> 1)];
            acc[nt] = __builtin_amdgcn_mfma_f32_16x16x32_bf16(af.v, b, acc[nt], 0, 0, 0);
        }
    }
#pragma unroll
    for (int r = 0; r < 4; ++r) {
        int m = rowbase + kg * 4 + r;
        float dd = dis[m];
        long obase = (long)m * 64;
#pragma unroll
        for (int nt = 0; nt < 8; ++nt) {
            float v = acc[nt][r] * dd;
            float v2 = __shfl_xor(v, 1);
            if ((l & 1) == 0)
                Yb[obase + nt * 8 + (ml >> 1)] = bf16pair(v, v2);
        }
    }
}

// ---------------- conv2 MFMA GEMM: bf16 input + fused BN1+ReLU ----------------
__global__ __launch_bounds__(256)
void k_gemm_bf16(const u32* __restrict__ Xb, const u32* __restrict__ Wt,
                 u32* __restrict__ Yb, const float* __restrict__ ss,
                 const float* __restrict__ dis) {
    int t = threadIdx.x;
    int l = t & 63, wv = t >> 6;
    int rowbase = blockIdx.x * 64 + wv * 16;
    int ml = l & 15, kg = l >> 4;

    f32x4 acc[8];
#pragma unroll
    for (int nt = 0; nt < 8; ++nt) acc[nt] = (f32x4){0.f, 0.f, 0.f, 0.f};
    const u32* xr = Xb + (long)(rowbase + ml) * 64;
#pragma unroll
    for (int kk = 0; kk < 4; ++kk) {
        int k0 = kk * 32 + kg * 8;
        uint4 xw = *(const uint4*)&xr[k0 >> 1];
        float f0 = bflo(xw.x), f1 = bfhi(xw.x), f2 = bflo(xw.y), f3 = bfhi(xw.y);
        float f4 = bflo(xw.z), f5 = bfhi(xw.z), f6 = bflo(xw.w), f7 = bfhi(xw.w);
        float4 sca = *(const float4*)&ss[k0];
        float4 sha = *(const float4*)&ss[128 + k0];
        float4 scb = *(const float4*)&ss[k0 + 4];
        float4 shb = *(const float4*)&ss[128 + k0 + 4];
        f0 = fmaxf(fmaf(f0, sca.x, sha.x), 0.f);
        f1 = fmaxf(fmaf(f1, sca.y, sha.y), 0.f);
        f2 = fmaxf(fmaf(f2, sca.z, sha.z), 0.f);
        f3 = fmaxf(fmaf(f3, sca.w, sha.w), 0.f);
        f4 = fmaxf(fmaf(f4, scb.x, shb.x), 0.f);
        f5 = fmaxf(fmaf(f5, scb.y, shb.y), 0.f);
        f6 = fmaxf(fmaf(f6, scb.z, shb.z), 0.f);
        f7 = fmaxf(fmaf(f7, scb.w, shb.w), 0.f);
        union { u32 u[4]; bf16x8 v; } af;
        af.u[0] = bf16pair(f0, f1);
        af.u[1] = bf16pair(f2, f3);
        af.u[2] = bf16pair(f4, f5);
        af.u[3] = bf16pair(f6, f7);
#pragma unroll
        for (int nt = 0; nt < 8; ++nt) {
            bf16x8 b = *(const bf16x8*)&Wt[(nt * 16 + ml) * 64 + (k0 >> 1)];
            acc[nt] = __builtin_amdgcn_mfma_f32_16x16x32_bf16(af.v, b, acc[nt], 0, 0, 0);
        }
    }
#pragma unroll
    for (int r = 0; r < 4; ++r) {
        int m = rowbase + kg * 4 + r;
        float dd = dis[m];
        long obase = (long)m * 64;
#pragma unroll
        for (int nt = 0; nt < 8; ++nt) {
            float v = acc[nt][r] * dd;
            float v2 = __shfl_xor(v, 1);
            if ((l & 1) == 0)
                Yb[obase + nt * 8 + (ml >> 1)] = bf16pair(v, v2);
        }
    }
}

// ---------------- gather + fused BN partial stats ----------------
// out rows (bf16) = dis[d]*(sum H'[s] + H'[d]) + bias ; per-thread stat accum over
// its fixed col pair; block partials -> part[GB][256]
__global__ __launch_bounds__(256)
void k_gather_stats(const uint4* __restrict__ Hb, const int* __restrict__ rowstart,
                    const int* __restrict__ csr_src, const float* __restrict__ dis,
                    const float* __restrict__ bias, u32* __restrict__ F1b,
                    float* __restrict__ part) {
    __shared__ float ls[1024], lq[1024];
    int t = threadIdx.x;
    int lane = t & 63, wv = t >> 6;
    int gw = blockIdx.x * 4 + wv;
    int g = lane >> 4, p = lane & 15;
    int c0 = p * 8 + g * 2;
    float2 bb = *(const float2*)&bias[c0];
    float s0 = 0.f, s1 = 0.f, q0 = 0.f, q1 = 0.f;

    for (int node = gw; node < NN; node += GB * 4) {
        float a0 = 0.f, a1 = 0.f, a2 = 0.f, a3 = 0.f, a4 = 0.f, a5 = 0.f, a6 = 0.f, a7 = 0.f;
        if (g == 0) {
            uint4 h = Hb[node * 16 + p];
            a0 = bflo(h.x); a1 = bfhi(h.x);
            a2 = bflo(h.y); a3 = bfhi(h.y);
            a4 = bflo(h.z); a5 = bfhi(h.z);
            a6 = bflo(h.w); a7 = bfhi(h.w);
        }
        int e1 = rowstart[node + 1];
        int e = rowstart[node] + g;
        for (; e + 4 < e1; e += 8) {
            int sA = csr_src[e];
            int sB = csr_src[e + 4];
            uint4 h0 = Hb[sA * 16 + p];
            uint4 h1 = Hb[sB * 16 + p];
            a0 += bflo(h0.x); a1 += bfhi(h0.x);
            a2 += bflo(h0.y); a3 += bfhi(h0.y);
            a4 += bflo(h0.z); a5 += bfhi(h0.z);
            a6 += bflo(h0.w); a7 += bfhi(h0.w);
            a0 += bflo(h1.x); a1 += bfhi(h1.x);
            a2 += bflo(h1.y); a3 += bfhi(h1.y);
            a4 += bflo(h1.z); a5 += bfhi(h1.z);
            a6 += bflo(h1.w); a7 += bfhi(h1.w);
        }
        if (e < e1) {
            int sA = csr_src[e];
            uint4 h0 = Hb[sA * 16 + p];
            a0 += bflo(h0.x); a1 += bfhi(h0.x);
            a2 += bflo(h0.y); a3 += bfhi(h0.y);
            a4 += bflo(h0.z); a5 += bfhi(h0.z);
            a6 += bflo(h0.w); a7 += bfhi(h0.w);
        }
#pragma unroll
        for (int m = 16; m <= 32; m <<= 1) {
            a0 += __shfl_xor(a0, m); a1 += __shfl_xor(a1, m);
            a2 += __shfl_xor(a2, m); a3 += __shfl_xor(a3, m);
            a4 += __shfl_xor(a4, m); a5 += __shfl_xor(a5, m);
            a6 += __shfl_xor(a6, m); a7 += __shfl_xor(a7, m);
        }
        float dd = dis[node];
        float x = (g == 0) ? a0 : (g == 1) ? a2 : (g == 2) ? a4 : a6;
        float y = (g == 0) ? a1 : (g == 1) ? a3 : (g == 2) ? a5 : a7;
        x = fmaf(x, dd, bb.x);
        y = fmaf(y, dd, bb.y);
        u32 pw = bf16pair(x, y);
        F1b[node * 64 + (c0 >> 1)] = pw;
        float rx = bflo(pw), ry = bfhi(pw);
        s0 += rx; s1 += ry; q0 += rx * rx; q1 += ry * ry;
    }
    ls[wv * 128 + c0] = s0; ls[wv * 128 + c0 + 1] = s1;
    lq[wv * 128 + c0] = q0; lq[wv * 128 + c0 + 1] = q1;
    __syncthreads();
    if (t < 128) {
        float S = ls[t] + ls[128 + t] + ls[256 + t] + ls[384 + t];
        float Q = lq[t] + lq[128 + t] + lq[256 + t] + lq[384 + t];
        part[blockIdx.x * 256 + t] = S;
        part[blockIdx.x * 256 + 128 + t] = Q;
    }
}

// ---------------- BN finalize from gather partials (one block per column) ----------------
__global__ __launch_bounds__(256)
void k_bnfinalw(const float* __restrict__ part, const float* __restrict__ g,
                const float* __restrict__ b, float* __restrict__ ss) {
    __shared__ float rs[256], rq[256];
    int c = blockIdx.x, t = threadIdx.x;
    float s = 0.f, q = 0.f;
    for (int i = t; i < GB; i += 256) {
        s += part[i * 256 + c];
        q += part[i * 256 + 128 + c];
    }
    rs[t] = s; rq[t] = q;
    __syncthreads();
    for (int off = 128; off > 0; off >>= 1) {
        if (t < off) { rs[t] += rs[t + off]; rq[t] += rq[t + off]; }
        __syncthreads();
    }
    if (t == 0) {
        float mean = rs[0] * (1.0f / NN);
        float var  = rq[0] * (1.0f / NN) - mean * mean;
        float sc = g[c] * rsqrtf(var + BNEPS);
        ss[c] = sc;
        ss[128 + c] = b[c] - mean * sc;
    }
}

// ---------------- k_cell: BN2+ReLU + emb write + scores(MFMA) + softmax + pool + fc head1 ----------------
__global__ __launch_bounds__(512, 1)
void k_cell(const u32* __restrict__ F1b, const float* __restrict__ ss,
            float* __restrict__ emb,
            const u32* __restrict__ Wta, const float* __restrict__ b1,
            const float* __restrict__ w2, const float* __restrict__ b2,
            const float* __restrict__ fc_w, const float* __restrict__ fc_b,
            float* __restrict__ y1pre, float* __restrict__ hstats) {
    __shared__ u32 xs[SUBG * 64];      // 102.4 KB bf16 tile (swizzled)
    __shared__ float sc[SUBG];
    __shared__ float red[512];
    __shared__ float pr[128];
    int c = blockIdx.x;
    int t = threadIdx.x;
    long gbase = (long)c * SUBG;

    // stage: unpack F1b -> BN2+ReLU -> emb (f32) + xs (bf16, swizzled)
    for (int i = t; i < SUBG * 64; i += 512) {
        int gg = i >> 6, cc = i & 63;
        u32 v = F1b[(gbase + gg) * 64 + cc];
        float x0 = bflo(v), x1 = bfhi(v);
        float2 scv = *(const float2*)&ss[2 * cc];
        float2 shv = *(const float2*)&ss[128 + 2 * cc];
        x0 = fmaxf(fmaf(x0, scv.x, shv.x), 0.f);
        x1 = fmaxf(fmaf(x1, scv.y, shv.y), 0.f);
        float2 o = { x0, x1 };
        *(float2*)&emb[(gbase + gg) * 128 + 2 * cc] = o;
        xs[gg * 64 + SWZ(gg, cc)] = bf16pair(x0, x1);
    }
    __syncthreads();

    // scores via MFMA: 25 gene-tiles of 16, hidden=64 (4 n-tiles)
    int l = t & 63, wv = t >> 6;
    int ml = l & 15, kg = l >> 4;
    bf16x8 bw[4][4];
#pragma unroll
    for (int nt = 0; nt < 4; ++nt)
#pragma unroll
        for (int kk = 0; kk < 4; ++kk)
            bw[nt][kk] = *(const bf16x8*)&Wta[(nt * 16 + ml) * 64 + (kk * 16 + kg * 4)];
    float b1v[4], w2v[4];
#pragma unroll
    for (int nt = 0; nt < 4; ++nt) {
        b1v[nt] = b1[nt * 16 + ml];
        w2v[nt] = w2[nt * 16 + ml];
    }
    float b2v = b2[0];

    for (int tile = wv; tile < 25; tile += 8) {
        int gg = tile * 16 + ml;
        f32x4 acc[4];
#pragma unroll
        for (int nt = 0; nt < 4; ++nt) acc[nt] = (f32x4){0.f, 0.f, 0.f, 0.f};
#pragma unroll
        for (int kk = 0; kk < 4; ++kk) {
            int cc4 = kk * 4 + kg;
            bf16x8 a = *(const bf16x8*)&xs[gg * 64 + ((cc4 ^ ml) << 2)];
#pragma unroll
            for (int nt = 0; nt < 4; ++nt)
                acc[nt] = __builtin_amdgcn_mfma_f32_16x16x32_bf16(a, bw[nt][kk], acc[nt], 0, 0, 0);
        }
#pragma unroll
        for (int r = 0; r < 4; ++r) {
            int g2 = tile * 16 + kg * 4 + r;
            float s = tanhf(acc[0][r] + b1v[0]) * w2v[0]
                    + tanhf(acc[1][r] + b1v[1]) * w2v[1]
                    + tanhf(acc[2][r] + b1v[2]) * w2v[2]
                    + tanhf(acc[3][r] + b1v[3]) * w2v[3];
            s += __shfl_xor(s, 1);
            s += __shfl_xor(s, 2);
            s += __shfl_xor(s, 4);
            s += __shfl_xor(s, 8);
            if (ml == 0) sc[g2] = s + b2v;
        }
    }
    __syncthreads();

    // softmax over 400
    red[t] = (t < SUBG) ? sc[t] : -1e30f;
    __syncthreads();
    for (int off = 256; off > 0; off >>= 1) {
        if (t < off) red[t] = fmaxf(red[t], red[t + off]);
        __syncthreads();
    }
    float mx = red[0];
    __syncthreads();
    float e = 0.f;
    if (t < SUBG) { e = __expf(sc[t] - mx); }
    red[t] = e;
    __syncthreads();
    for (int off = 256; off > 0; off >>= 1) {
        if (t < off) red[t] += red[t + off];
        __syncthreads();
    }
    float inv = 1.0f / red[0];
    __syncthreads();
    if (t < SUBG) sc[t] = e * inv;
    __syncthreads();

    // pooled: col = t&127 over gene stripes
    int col = t & 127, grp = t >> 7;
    int cc = col >> 1, lohi = col & 1;
    float acc = 0.f;
    for (int gg = grp; gg < SUBG; gg += 4) {
        u32 v = xs[gg * 64 + SWZ(gg, cc)];
        float val = lohi ? bfhi(v) : bflo(v);
        acc += sc[gg] * val;
    }
    red[t] = acc;
    __syncthreads();
    if (t < 128) pr[col] = red[col] + red[128 + col] + red[256 + col] + red[384 + col];
    __syncthreads();

    // head1: y1pre[c] = pooled @ fc_w + fc_b, + atomic BN stats
    if (t < 128) {
        float a1 = fc_b[t];
#pragma unroll 4
        for (int k = 0; k < 128; ++k) a1 = fmaf(pr[k], fc_w[k * 128 + t], a1);
        y1pre[c * 128 + t] = a1;
        atomicAdd(&hstats[t], a1);
        atomicAdd(&hstats[128 + t], a1 * a1);
    }
}

// ---------------- head2: finalize BN-e, apply, bottleneck, atomic stats2 ----------------
__global__ __launch_bounds__(128)
void k_head2s(const float* __restrict__ y1pre, const float* __restrict__ hstats,
              const float* __restrict__ bne_g, const float* __restrict__ bne_b,
              const float* __restrict__ bot_w, const float* __restrict__ bot_b,
              float* __restrict__ y2pre, float* __restrict__ hstats2) {
    __shared__ float row[128];
    int c = blockIdx.x, t = threadIdx.x;
    float s = hstats[t], q = hstats[128 + t];
    float mean = s * 0.01f, var = q * 0.01f - mean * mean;
    float scv = bne_g[t] * rsqrtf(var + BNEPS);
    float shv = bne_b[t] - mean * scv;
    row[t] = fmaxf(fmaf(y1pre[c * 128 + t], scv, shv), 0.f);
    __syncthreads();
    if (t < 32) {
        float a2 = bot_b[t];
#pragma unroll 4
        for (int k = 0; k < 128; ++k) a2 = fmaf(row[k], bot_w[k * 32 + t], a2);
        y2pre[c * 32 + t] = a2;
        atomicAdd(&hstats2[t], a2);
        atomicAdd(&hstats2[32 + t], a2 * a2);
    }
}

// ---------------- final: BN-b finalize + apply ----------------
__global__ __launch_bounds__(256)
void k_out(const float* __restrict__ y2pre, const float* __restrict__ hstats2,
           const float* __restrict__ bnb_g, const float* __restrict__ bnb_b,
           float* __restrict__ y_out) {
    __shared__ float scv[32], shv[32];
    int t = threadIdx.x;
    if (t < 32) {
        float s = hstats2[t], q = hstats2[32 + t];
        float mean = s * 0.01f, var = q * 0.01f - mean * mean;
        float v = bnb_g[t] * rsqrtf(var + BNEPS);
        scv[t] = v; shv[t] = bnb_b[t] - mean * v;
    }
    __syncthreads();
    for (int i = t; i < CELLS * 32; i += 256)
        y_out[i] = fmaxf(fmaf(y2pre[i], scv[i & 31], shv[i & 31]), 0.f);
}

// ---------------- launcher ----------------
extern "C" void kernel_launch(void* const* d_in, const int* in_sizes, int n_in,
                              void* d_out, int out_size, void* d_ws, size_t ws_size,
                              hipStream_t stream) {
    const float* x        = (const float*)d_in[0];
    const int*   ei       = (const int*)d_in[1];
    const float* conv1_w  = (const float*)d_in[2];
    const float* conv1_b  = (const float*)d_in[3];
    const float* bn1_g    = (const float*)d_in[4];
    const float* bn1_b    = (const float*)d_in[5];
    const float* conv2_w  = (const float*)d_in[6];
    const float* conv2_b  = (const float*)d_in[7];
    const float* bn2_g    = (const float*)d_in[8];
    const float* bn2_b    = (const float*)d_in[9];
    const float* att_w1   = (const float*)d_in[10];
    const float* att_b1   = (const float*)d_in[11];
    const float* att_w2   = (const float*)d_in[12];
    const float* att_b2   = (const float*)d_in[13];
    const float* fc_w     = (const float*)d_in[14];
    const float* fc_b     = (const float*)d_in[15];
    const float* bne_g    = (const float*)d_in[16];
    const float* bne_b    = (const float*)d_in[17];
    const float* bot_w    = (const float*)d_in[18];
    const float* bot_b    = (const float*)d_in[19];
    const float* bnb_g    = (const float*)d_in[20];
    const float* bnb_b    = (const float*)d_in[21];

    const int* src = ei;
    const int* dst = ei + EE;

    float* y_out   = (float*)d_out;            // [100,32]
    float* emb_out = y_out + CELLS * 32;       // [40000,128]

    float* ws = (float*)d_ws;
    u32*   Hb     = (u32*)ws;                  // N*64 (10.25 MB)
    u32*   F1b    = Hb + (long)NN * 64;        // N*64 (10.25 MB)
    float* dis    = (float*)(F1b + (long)NN * 64);  // N
    float* part   = dis + NN;                  // GB*256 (2 MB)
    float* ss     = part + GB * 256;           // 256
    float* hstats = ss + 256;                  // 320 (256 bne + 64 bnb)
    float* y1pre  = hstats + 320;              // C*128
    float* y2pre  = y1pre + CELLS * 128;       // C*32
    u32*   Wt1    = (u32*)(y2pre + CELLS * 32);// 8192
    u32*   Wt2    = Wt1 + 8192;                // 8192
    u32*   Wta    = Wt2 + 8192;                // 4096
    int*   deg    = (int*)(Wta + 4096);        // N  (deg + cursor contiguous)
    int*   cursor = deg + NN;                  // N
    int*   rowstart = cursor + NN;             // N+1
    int*   csr_src  = rowstart + NN + 1;       // E

    // 1. init (zero deg/cursor/hstats, bf16 weight transposes)
    k_init<<<394, 256, 0, stream>>>(deg, conv1_w, Wt1, conv2_w, Wt2, att_w1, Wta, hstats);
    // 2. degree count
    k_degcount<<<512, 256, 0, stream>>>(dst, deg);
    // 3. scan -> rowstart, dis
    k_scan<<<1, 1024, 0, stream>>>(deg, rowstart, dis);
    // 4. fill CSR || conv1 GEMM
    k_fillgemm<<<GEMMB + FILLB, 256, 0, stream>>>(x, Wt1, Hb, dis, src, dst,
                                                  rowstart, cursor, csr_src);
    // 5-6. conv1 gather+stats, BN1 finalize
    k_gather_stats<<<GB, 256, 0, stream>>>((const uint4*)Hb, rowstart, csr_src, dis,
                                           conv1_b, F1b, part);
    k_bnfinalw<<<128, 256, 0, stream>>>(part, bn1_g, bn1_b, ss);
    // 7. conv2 GEMM (bf16 in, BN1+ReLU fused)
    k_gemm_bf16<<<GEMMB, 256, 0, stream>>>(F1b, Wt2, Hb, ss, dis);
    // 8-9. conv2 gather+stats, BN2 finalize
    k_gather_stats<<<GB, 256, 0, stream>>>((const uint4*)Hb, rowstart, csr_src, dis,
                                           conv2_b, F1b, part);
    k_bnfinalw<<<128, 256, 0, stream>>>(part, bn2_g, bn2_b, ss);
    // 10. per-cell mega kernel: BN2 apply + emb + scores + softmax + pool + head1
    k_cell<<<CELLS, 512, 0, stream>>>(F1b, ss, emb_out, Wta, att_b1, att_w2, att_b2,
                                      fc_w, fc_b, y1pre, hstats);
    // 11. head2 + stats2
    k_head2s<<<CELLS, 128, 0, stream>>>(y1pre, hstats, bne_g, bne_b, bot_w, bot_b,
                                        y2pre, hstats + 256);
    // 12. final BN + output
    k_out<<<1, 256, 0, stream>>>(y2pre, hstats + 256, bnb_g, bnb_b, y_out);
}

// Round 10
// 244.418 us; speedup vs baseline: 1.6164x; 1.1460x over previous
//
#include <hip/hip_runtime.h>
#include <math.h>

typedef unsigned int u32;
typedef __attribute__((ext_vector_type(8))) short bf16x8;
typedef __attribute__((ext_vector_type(4))) float f32x4;

#define NN   40000
#define EE   640000
#define SUBG 400
#define CELLS 100
#define BNEPS 1e-5f
#define GB   2048      // gather blocks (8192 waves = 32/CU)
#define GEMMB 625
#define FILLB 1024

// ---- bf16 helpers ----
__device__ __forceinline__ u32 bf16pair(float a, float b) {
    u32 ua = __float_as_uint(a), ub = __float_as_uint(b);
    ua += 0x7fffu + ((ua >> 16) & 1u);
    ub += 0x7fffu + ((ub >> 16) & 1u);
    return (ua >> 16) | (ub & 0xffff0000u);
}
__device__ __forceinline__ float bflo(u32 u) { return __uint_as_float(u << 16); }
__device__ __forceinline__ float bfhi(u32 u) { return __uint_as_float(u & 0xffff0000u); }

// LDS swizzle for k_cell tile: permute 16B chunks within a row keyed by row
#define SWZ(g, cc) ( ((cc) & 3) | (((((cc) >> 2) ^ ((g) & 15))) << 2) )

// ---------------- init: zero deg/cursor + bf16-transpose weights + zero head stats ----------------
__global__ void k_init(int* deg_cursor, const float* W1, u32* Wt1,
                       const float* W2, u32* Wt2, const float* wa, u32* Wta,
                       float* hstats) {
    int i = blockIdx.x * 256 + threadIdx.x;
    if (i < 2 * NN) { deg_cursor[i] = 0; return; }
    i -= 2 * NN;
    if (i < 16384) {
        const float* W = (i < 8192) ? W1 : W2;
        u32* Wt = (i < 8192) ? Wt1 : Wt2;
        int j = i & 8191;
        int n = j >> 6, k2 = (j & 63) * 2;
        Wt[n * 64 + (j & 63)] = bf16pair(W[k2 * 128 + n], W[(k2 + 1) * 128 + n]);
        return;
    }
    i -= 16384;
    if (i < 4096) {
        int n = i >> 6, k2 = (i & 63) * 2;
        Wta[n * 64 + (i & 63)] = bf16pair(wa[k2 * 64 + n], wa[(k2 + 1) * 64 + n]);
        return;
    }
    i -= 4096;
    if (i < 320) hstats[i] = 0.f;
}

// ---------------- degree count ----------------
__global__ void k_degcount(const int* __restrict__ dst, int* __restrict__ deg) {
    int i = blockIdx.x * blockDim.x + threadIdx.x;
    int stride = gridDim.x * blockDim.x;
    for (; i < EE; i += stride) atomicAdd(&deg[dst[i]], 1);
}

// ---------------- single-block full exclusive scan + dis (two-pass, no spill) ----------------
__global__ __launch_bounds__(1024)
void k_scan(const int* __restrict__ deg, int* __restrict__ rowstart,
            float* __restrict__ dis) {
    __shared__ int ps[1024];
    int t = threadIdx.x;
    const int4* d4 = (const int4*)deg;   // 10000 int4 total; thread t owns [t*10, t*10+10)
    int sum = 0;
#pragma unroll
    for (int j = 0; j < 10; ++j) {
        int i4 = t * 10 + j;
        if (i4 < 10000) {
            int4 v = d4[i4];
            sum += v.x + v.y + v.z + v.w;
        }
    }
    ps[t] = sum;
    __syncthreads();
    for (int off = 1; off < 1024; off <<= 1) {
        int add = (t >= off) ? ps[t - off] : 0;
        __syncthreads();
        ps[t] += add;
        __syncthreads();
    }
    int run = ps[t] - sum;
#pragma unroll
    for (int j = 0; j < 10; ++j) {
        int i4 = t * 10 + j;
        if (i4 < 10000) {
            int4 v = d4[i4];      // L1/L2-hot re-read
            int4 r;
            r.x = run;
            r.y = run + v.x;
            r.z = r.y + v.y;
            r.w = r.z + v.z;
            run = r.w + v.w;
            *(int4*)&rowstart[i4 * 4] = r;
            float4 dv;
            dv.x = rsqrtf((float)(v.x + 1));
            dv.y = rsqrtf((float)(v.y + 1));
            dv.z = rsqrtf((float)(v.z + 1));
            dv.w = rsqrtf((float)(v.w + 1));
            *(float4*)&dis[i4 * 4] = dv;
        }
    }
    if (t == 0) rowstart[NN] = EE;
}

// ---------------- fill CSR  ||  conv1 MFMA GEMM (merged dispatch) ----------------
__global__ __launch_bounds__(256)
void k_fillgemm(const float* __restrict__ X, const u32* __restrict__ Wt,
                u32* __restrict__ Yb, const float* __restrict__ dis,
                const int* __restrict__ src, const int* __restrict__ dst,
                const int* __restrict__ rowstart, int* __restrict__ cursor,
                int* __restrict__ csr_src) {
    int bid = blockIdx.x;
    int t = threadIdx.x;
    if (bid >= GEMMB) {
        int i = (bid - GEMMB) * 256 + t;
        int stride = FILLB * 256;
        for (; i < EE; i += stride) {
            int d = dst[i];
            int slot = rowstart[d] + atomicAdd(&cursor[d], 1);
            csr_src[slot] = src[i];
        }
        return;
    }
    int l = t & 63, wv = t >> 6;
    int rowbase = bid * 64 + wv * 16;
    int ml = l & 15, kg = l >> 4;

    f32x4 acc[8];
#pragma unroll
    for (int nt = 0; nt < 8; ++nt) acc[nt] = (f32x4){0.f, 0.f, 0.f, 0.f};
    const float* xr = X + (long)(rowbase + ml) * 128;
#pragma unroll
    for (int kk = 0; kk < 4; ++kk) {
        int k0 = kk * 32 + kg * 8;
        float4 xa = *(const float4*)&xr[k0];
        float4 xb = *(const float4*)&xr[k0 + 4];
        union { u32 u[4]; bf16x8 v; } af;
        af.u[0] = bf16pair(xa.x, xa.y);
        af.u[1] = bf16pair(xa.z, xa.w);
        af.u[2] = bf16pair(xb.x, xb.y);
        af.u[3] = bf16pair(xb.z, xb.w);
#pragma unroll
        for (int nt = 0; nt < 8; ++nt) {
            bf16x8 b = *(const bf16x8*)&Wt[(nt * 16 + ml) * 64 + (k0 >> 1)];
            acc[nt] = __builtin_amdgcn_mfma_f32_16x16x32_bf16(af.v, b, acc[nt], 0, 0, 0);
        }
    }
#pragma unroll
    for (int r = 0; r < 4; ++r) {
        int m = rowbase + kg * 4 + r;
        float dd = dis[m];
        long obase = (long)m * 64;
#pragma unroll
        for (int nt = 0; nt < 8; ++nt) {
            float v = acc[nt][r] * dd;
            float v2 = __shfl_xor(v, 1);
            if ((l & 1) == 0)
                Yb[obase + nt * 8 + (ml >> 1)] = bf16pair(v, v2);
        }
    }
}

// ---------------- conv2 MFMA GEMM: bf16 input + fused BN1+ReLU ----------------
__global__ __launch_bounds__(256)
void k_gemm_bf16(const u32* __restrict__ Xb, const u32* __restrict__ Wt,
                 u32* __restrict__ Yb, const float* __restrict__ ss,
                 const float* __restrict__ dis) {
    int t = threadIdx.x;
    int l = t & 63, wv = t >> 6;
    int rowbase = blockIdx.x * 64 + wv * 16;
    int ml = l & 15, kg = l >> 4;

    f32x4 acc[8];
#pragma unroll
    for (int nt = 0; nt < 8; ++nt) acc[nt] = (f32x4){0.f, 0.f, 0.f, 0.f};
    const u32* xr = Xb + (long)(rowbase + ml) * 64;
#pragma unroll
    for (int kk = 0; kk < 4; ++kk) {
        int k0 = kk * 32 + kg * 8;
        uint4 xw = *(const uint4*)&xr[k0 >> 1];
        float f0 = bflo(xw.x), f1 = bfhi(xw.x), f2 = bflo(xw.y), f3 = bfhi(xw.y);
        float f4 = bflo(xw.z), f5 = bfhi(xw.z), f6 = bflo(xw.w), f7 = bfhi(xw.w);
        float4 sca = *(const float4*)&ss[k0];
        float4 sha = *(const float4*)&ss[128 + k0];
        float4 scb = *(const float4*)&ss[k0 + 4];
        float4 shb = *(const float4*)&ss[128 + k0 + 4];
        f0 = fmaxf(fmaf(f0, sca.x, sha.x), 0.f);
        f1 = fmaxf(fmaf(f1, sca.y, sha.y), 0.f);
        f2 = fmaxf(fmaf(f2, sca.z, sha.z), 0.f);
        f3 = fmaxf(fmaf(f3, sca.w, sha.w), 0.f);
        f4 = fmaxf(fmaf(f4, scb.x, shb.x), 0.f);
        f5 = fmaxf(fmaf(f5, scb.y, shb.y), 0.f);
        f6 = fmaxf(fmaf(f6, scb.z, shb.z), 0.f);
        f7 = fmaxf(fmaf(f7, scb.w, shb.w), 0.f);
        union { u32 u[4]; bf16x8 v; } af;
        af.u[0] = bf16pair(f0, f1);
        af.u[1] = bf16pair(f2, f3);
        af.u[2] = bf16pair(f4, f5);
        af.u[3] = bf16pair(f6, f7);
#pragma unroll
        for (int nt = 0; nt < 8; ++nt) {
            bf16x8 b = *(const bf16x8*)&Wt[(nt * 16 + ml) * 64 + (k0 >> 1)];
            acc[nt] = __builtin_amdgcn_mfma_f32_16x16x32_bf16(af.v, b, acc[nt], 0, 0, 0);
        }
    }
#pragma unroll
    for (int r = 0; r < 4; ++r) {
        int m = rowbase + kg * 4 + r;
        float dd = dis[m];
        long obase = (long)m * 64;
#pragma unroll
        for (int nt = 0; nt < 8; ++nt) {
            float v = acc[nt][r] * dd;
            float v2 = __shfl_xor(v, 1);
            if ((l & 1) == 0)
                Yb[obase + nt * 8 + (ml >> 1)] = bf16pair(v, v2);
        }
    }
}

// ---------------- gather + fused BN partial stats ----------------
__global__ __launch_bounds__(256)
void k_gather_stats(const uint4* __restrict__ Hb, const int* __restrict__ rowstart,
                    const int* __restrict__ csr_src, const float* __restrict__ dis,
                    const float* __restrict__ bias, u32* __restrict__ F1b,
                    float* __restrict__ part) {
    __shared__ float ls[1024], lq[1024];
    int t = threadIdx.x;
    int lane = t & 63, wv = t >> 6;
    int gw = blockIdx.x * 4 + wv;
    int g = lane >> 4, p = lane & 15;
    int c0 = p * 8 + g * 2;
    float2 bb = *(const float2*)&bias[c0];
    float s0 = 0.f, s1 = 0.f, q0 = 0.f, q1 = 0.f;

    for (int node = gw; node < NN; node += GB * 4) {
        float a0 = 0.f, a1 = 0.f, a2 = 0.f, a3 = 0.f, a4 = 0.f, a5 = 0.f, a6 = 0.f, a7 = 0.f;
        if (g == 0) {
            uint4 h = Hb[node * 16 + p];
            a0 = bflo(h.x); a1 = bfhi(h.x);
            a2 = bflo(h.y); a3 = bfhi(h.y);
            a4 = bflo(h.z); a5 = bfhi(h.z);
            a6 = bflo(h.w); a7 = bfhi(h.w);
        }
        int e1 = rowstart[node + 1];
        int e = rowstart[node] + g;
        for (; e + 4 < e1; e += 8) {
            int sA = csr_src[e];
            int sB = csr_src[e + 4];
            uint4 h0 = Hb[sA * 16 + p];
            uint4 h1 = Hb[sB * 16 + p];
            a0 += bflo(h0.x); a1 += bfhi(h0.x);
            a2 += bflo(h0.y); a3 += bfhi(h0.y);
            a4 += bflo(h0.z); a5 += bfhi(h0.z);
            a6 += bflo(h0.w); a7 += bfhi(h0.w);
            a0 += bflo(h1.x); a1 += bfhi(h1.x);
            a2 += bflo(h1.y); a3 += bfhi(h1.y);
            a4 += bflo(h1.z); a5 += bfhi(h1.z);
            a6 += bflo(h1.w); a7 += bfhi(h1.w);
        }
        if (e < e1) {
            int sA = csr_src[e];
            uint4 h0 = Hb[sA * 16 + p];
            a0 += bflo(h0.x); a1 += bfhi(h0.x);
            a2 += bflo(h0.y); a3 += bfhi(h0.y);
            a4 += bflo(h0.z); a5 += bfhi(h0.z);
            a6 += bflo(h0.w); a7 += bfhi(h0.w);
        }
#pragma unroll
        for (int m = 16; m <= 32; m <<= 1) {
            a0 += __shfl_xor(a0, m); a1 += __shfl_xor(a1, m);
            a2 += __shfl_xor(a2, m); a3 += __shfl_xor(a3, m);
            a4 += __shfl_xor(a4, m); a5 += __shfl_xor(a5, m);
            a6 += __shfl_xor(a6, m); a7 += __shfl_xor(a7, m);
        }
        float dd = dis[node];
        float x = (g == 0) ? a0 : (g == 1) ? a2 : (g == 2) ? a4 : a6;
        float y = (g == 0) ? a1 : (g == 1) ? a3 : (g == 2) ? a5 : a7;
        x = fmaf(x, dd, bb.x);
        y = fmaf(y, dd, bb.y);
        u32 pw = bf16pair(x, y);
        F1b[node * 64 + (c0 >> 1)] = pw;
        float rx = bflo(pw), ry = bfhi(pw);
        s0 += rx; s1 += ry; q0 += rx * rx; q1 += ry * ry;
    }
    ls[wv * 128 + c0] = s0; ls[wv * 128 + c0 + 1] = s1;
    lq[wv * 128 + c0] = q0; lq[wv * 128 + c0 + 1] = q1;
    __syncthreads();
    if (t < 128) {
        float S = ls[t] + ls[128 + t] + ls[256 + t] + ls[384 + t];
        float Q = lq[t] + lq[128 + t] + lq[256 + t] + lq[384 + t];
        part[blockIdx.x * 256 + t] = S;
        part[blockIdx.x * 256 + 128 + t] = Q;
    }
}

// ---------------- BN finalize from gather partials (one block per column) ----------------
__global__ __launch_bounds__(256)
void k_bnfinalw(const float* __restrict__ part, const float* __restrict__ g,
                const float* __restrict__ b, float* __restrict__ ss) {
    __shared__ float rs[256], rq[256];
    int c = blockIdx.x, t = threadIdx.x;
    float s = 0.f, q = 0.f;
    for (int i = t; i < GB; i += 256) {
        s += part[i * 256 + c];
        q += part[i * 256 + 128 + c];
    }
    rs[t] = s; rq[t] = q;
    __syncthreads();
    for (int off = 128; off > 0; off >>= 1) {
        if (t < off) { rs[t] += rs[t + off]; rq[t] += rq[t + off]; }
        __syncthreads();
    }
    if (t == 0) {
        float mean = rs[0] * (1.0f / NN);
        float var  = rq[0] * (1.0f / NN) - mean * mean;
        float sc = g[c] * rsqrtf(var + BNEPS);
        ss[c] = sc;
        ss[128 + c] = b[c] - mean * sc;
    }
}

// ---------------- k_cell: BN2+ReLU + emb write + scores(MFMA) + softmax + pool + fc head1 ----------------
__global__ __launch_bounds__(512, 1)
void k_cell(const u32* __restrict__ F1b, const float* __restrict__ ss,
            float* __restrict__ emb,
            const u32* __restrict__ Wta, const float* __restrict__ b1,
            const float* __restrict__ w2, const float* __restrict__ b2,
            const float* __restrict__ fc_w, const float* __restrict__ fc_b,
            float* __restrict__ y1pre, float* __restrict__ hstats) {
    __shared__ u32 xs[SUBG * 64];      // 102.4 KB bf16 tile (swizzled)
    __shared__ float sc[SUBG];
    __shared__ float red[512];
    __shared__ float pr[128];
    int c = blockIdx.x;
    int t = threadIdx.x;
    long gbase = (long)c * SUBG;

    for (int i = t; i < SUBG * 64; i += 512) {
        int gg = i >> 6, cc = i & 63;
        u32 v = F1b[(gbase + gg) * 64 + cc];
        float x0 = bflo(v), x1 = bfhi(v);
        float2 scv = *(const float2*)&ss[2 * cc];
        float2 shv = *(const float2*)&ss[128 + 2 * cc];
        x0 = fmaxf(fmaf(x0, scv.x, shv.x), 0.f);
        x1 = fmaxf(fmaf(x1, scv.y, shv.y), 0.f);
        float2 o = { x0, x1 };
        *(float2*)&emb[(gbase + gg) * 128 + 2 * cc] = o;
        xs[gg * 64 + SWZ(gg, cc)] = bf16pair(x0, x1);
    }
    __syncthreads();

    int l = t & 63, wv = t >> 6;
    int ml = l & 15, kg = l >> 4;
    bf16x8 bw[4][4];
#pragma unroll
    for (int nt = 0; nt < 4; ++nt)
#pragma unroll
        for (int kk = 0; kk < 4; ++kk)
            bw[nt][kk] = *(const bf16x8*)&Wta[(nt * 16 + ml) * 64 + (kk * 16 + kg * 4)];
    float b1v[4], w2v[4];
#pragma unroll
    for (int nt = 0; nt < 4; ++nt) {
        b1v[nt] = b1[nt * 16 + ml];
        w2v[nt] = w2[nt * 16 + ml];
    }
    float b2v = b2[0];

    for (int tile = wv; tile < 25; tile += 8) {
        int gg = tile * 16 + ml;
        f32x4 acc[4];
#pragma unroll
        for (int nt = 0; nt < 4; ++nt) acc[nt] = (f32x4){0.f, 0.f, 0.f, 0.f};
#pragma unroll
        for (int kk = 0; kk < 4; ++kk) {
            int cc4 = kk * 4 + kg;
            bf16x8 a = *(const bf16x8*)&xs[gg * 64 + ((cc4 ^ ml) << 2)];
#pragma unroll
            for (int nt = 0; nt < 4; ++nt)
                acc[nt] = __builtin_amdgcn_mfma_f32_16x16x32_bf16(a, bw[nt][kk], acc[nt], 0, 0, 0);
        }
#pragma unroll
        for (int r = 0; r < 4; ++r) {
            int g2 = tile * 16 + kg * 4 + r;
            float s = tanhf(acc[0][r] + b1v[0]) * w2v[0]
                    + tanhf(acc[1][r] + b1v[1]) * w2v[1]
                    + tanhf(acc[2][r] + b1v[2]) * w2v[2]
                    + tanhf(acc[3][r] + b1v[3]) * w2v[3];
            s += __shfl_xor(s, 1);
            s += __shfl_xor(s, 2);
            s += __shfl_xor(s, 4);
            s += __shfl_xor(s, 8);
            if (ml == 0) sc[g2] = s + b2v;
        }
    }
    __syncthreads();

    red[t] = (t < SUBG) ? sc[t] : -1e30f;
    __syncthreads();
    for (int off = 256; off > 0; off >>= 1) {
        if (t < off) red[t] = fmaxf(red[t], red[t + off]);
        __syncthreads();
    }
    float mx = red[0];
    __syncthreads();
    float e = 0.f;
    if (t < SUBG) { e = __expf(sc[t] - mx); }
    red[t] = e;
    __syncthreads();
    for (int off = 256; off > 0; off >>= 1) {
        if (t < off) red[t] += red[t + off];
        __syncthreads();
    }
    float inv = 1.0f / red[0];
    __syncthreads();
    if (t < SUBG) sc[t] = e * inv;
    __syncthreads();

    int col = t & 127, grp = t >> 7;
    int cc = col >> 1, lohi = col & 1;
    float acc = 0.f;
    for (int gg = grp; gg < SUBG; gg += 4) {
        u32 v = xs[gg * 64 + SWZ(gg, cc)];
        float val = lohi ? bfhi(v) : bflo(v);
        acc += sc[gg] * val;
    }
    red[t] = acc;
    __syncthreads();
    if (t < 128) pr[col] = red[col] + red[128 + col] + red[256 + col] + red[384 + col];
    __syncthreads();

    if (t < 128) {
        float a1 = fc_b[t];
#pragma unroll 4
        for (int k = 0; k < 128; ++k) a1 = fmaf(pr[k], fc_w[k * 128 + t], a1);
        y1pre[c * 128 + t] = a1;
        atomicAdd(&hstats[t], a1);
        atomicAdd(&hstats[128 + t], a1 * a1);
    }
}

// ---------------- head2: finalize BN-e, apply, bottleneck, atomic stats2 ----------------
__global__ __launch_bounds__(128)
void k_head2s(const float* __restrict__ y1pre, const float* __restrict__ hstats,
              const float* __restrict__ bne_g, const float* __restrict__ bne_b,
              const float* __restrict__ bot_w, const float* __restrict__ bot_b,
              float* __restrict__ y2pre, float* __restrict__ hstats2) {
    __shared__ float row[128];
    int c = blockIdx.x, t = threadIdx.x;
    float s = hstats[t], q = hstats[128 + t];
    float mean = s * 0.01f, var = q * 0.01f - mean * mean;
    float scv = bne_g[t] * rsqrtf(var + BNEPS);
    float shv = bne_b[t] - mean * scv;
    row[t] = fmaxf(fmaf(y1pre[c * 128 + t], scv, shv), 0.f);
    __syncthreads();
    if (t < 32) {
        float a2 = bot_b[t];
#pragma unroll 4
        for (int k = 0; k < 128; ++k) a2 = fmaf(row[k], bot_w[k * 32 + t], a2);
        y2pre[c * 32 + t] = a2;
        atomicAdd(&hstats2[t], a2);
        atomicAdd(&hstats2[32 + t], a2 * a2);
    }
}

// ---------------- final: BN-b finalize + apply ----------------
__global__ __launch_bounds__(256)
void k_out(const float* __restrict__ y2pre, const float* __restrict__ hstats2,
           const float* __restrict__ bnb_g, const float* __restrict__ bnb_b,
           float* __restrict__ y_out) {
    __shared__ float scv[32], shv[32];
    int t = threadIdx.x;
    if (t < 32) {
        float s = hstats2[t], q = hstats2[32 + t];
        float mean = s * 0.01f, var = q * 0.01f - mean * mean;
        float v = bnb_g[t] * rsqrtf(var + BNEPS);
        scv[t] = v; shv[t] = bnb_b[t] - mean * v;
    }
    __syncthreads();
    for (int i = t; i < CELLS * 32; i += 256)
        y_out[i] = fmaxf(fmaf(y2pre[i], scv[i & 31], shv[i & 31]), 0.f);
}

// ---------------- launcher ----------------
extern "C" void kernel_launch(void* const* d_in, const int* in_sizes, int n_in,
                              void* d_out, int out_size, void* d_ws, size_t ws_size,
                              hipStream_t stream) {
    const float* x        = (const float*)d_in[0];
    const int*   ei       = (const int*)d_in[1];
    const float* conv1_w  = (const float*)d_in[2];
    const float* conv1_b  = (const float*)d_in[3];
    const float* bn1_g    = (const float*)d_in[4];
    const float* bn1_b    = (const float*)d_in[5];
    const float* conv2_w  = (const float*)d_in[6];
    const float* conv2_b  = (const float*)d_in[7];
    const float* bn2_g    = (const float*)d_in[8];
    const float* bn2_b    = (const float*)d_in[9];
    const float* att_w1   = (const float*)d_in[10];
    const float* att_b1   = (const float*)d_in[11];
    const float* att_w2   = (const float*)d_in[12];
    const float* att_b2   = (const float*)d_in[13];
    const float* fc_w     = (const float*)d_in[14];
    const float* fc_b     = (const float*)d_in[15];
    const float* bne_g    = (const float*)d_in[16];
    const float* bne_b    = (const float*)d_in[17];
    const float* bot_w    = (const float*)d_in[18];
    const float* bot_b    = (const float*)d_in[19];
    const float* bnb_g    = (const float*)d_in[20];
    const float* bnb_b    = (const float*)d_in[21];

    const int* src = ei;
    const int* dst = ei + EE;

    float* y_out   = (float*)d_out;            // [100,32]
    float* emb_out = y_out + CELLS * 32;       // [40000,128]

    float* ws = (float*)d_ws;
    u32*   Hb     = (u32*)ws;                  // N*64 (10.25 MB)
    u32*   F1b    = Hb + (long)NN * 64;        // N*64 (10.25 MB)
    float* dis    = (float*)(F1b + (long)NN * 64);  // N
    float* part   = dis + NN;                  // GB*256 (2 MB)
    float* ss     = part + GB * 256;           // 256
    float* hstats = ss + 256;                  // 320 (256 bne + 64 bnb)
    float* y1pre  = hstats + 320;              // C*128
    float* y2pre  = y1pre + CELLS * 128;       // C*32
    u32*   Wt1    = (u32*)(y2pre + CELLS * 32);// 8192
    u32*   Wt2    = Wt1 + 8192;                // 8192
    u32*   Wta    = Wt2 + 8192;                // 4096
    int*   deg    = (int*)(Wta + 4096);        // N  (deg + cursor contiguous)
    int*   cursor = deg + NN;                  // N
    int*   rowstart = cursor + NN;             // N+1
    int*   csr_src  = rowstart + NN + 1;       // E

    // 1. init (zero deg/cursor/hstats, bf16 weight transposes)
    k_init<<<394, 256, 0, stream>>>(deg, conv1_w, Wt1, conv2_w, Wt2, att_w1, Wta, hstats);
    // 2. degree count
    k_degcount<<<512, 256, 0, stream>>>(dst, deg);
    // 3. scan -> rowstart, dis
    k_scan<<<1, 1024, 0, stream>>>(deg, rowstart, dis);
    // 4. fill CSR || conv1 GEMM
    k_fillgemm<<<GEMMB + FILLB, 256, 0, stream>>>(x, Wt1, Hb, dis, src, dst,
                                                  rowstart, cursor, csr_src);
    // 5-6. conv1 gather+stats, BN1 finalize
    k_gather_stats<<<GB, 256, 0, stream>>>((const uint4*)Hb, rowstart, csr_src, dis,
                                           conv1_b, F1b, part);
    k_bnfinalw<<<128, 256, 0, stream>>>(part, bn1_g, bn1_b, ss);
    // 7. conv2 GEMM (bf16 in, BN1+ReLU fused)
    k_gemm_bf16<<<GEMMB, 256, 0, stream>>>(F1b, Wt2, Hb, ss, dis);
    // 8-9. conv2 gather+stats, BN2 finalize
    k_gather_stats<<<GB, 256, 0, stream>>>((const uint4*)Hb, rowstart, csr_src, dis,
                                           conv2_b, F1b, part);
    k_bnfinalw<<<128, 256, 0, stream>>>(part, bn2_g, bn2_b, ss);
    // 10. per-cell mega kernel: BN2 apply + emb + scores + softmax + pool + head1
    k_cell<<<CELLS, 512, 0, stream>>>(F1b, ss, emb_out, Wta, att_b1, att_w2, att_b2,
                                      fc_w, fc_b, y1pre, hstats);
    // 11. head2 + stats2
    k_head2s<<<CELLS, 128, 0, stream>>>(y1pre, hstats, bne_g, bne_b, bot_w, bot_b,
                                        y2pre, hstats + 256);
    // 12. final BN + output
    k_out<<<1, 256, 0, stream>>>(y2pre, hstats + 256, bnb_g, bnb_b, y_out);
}

// Round 11
// 236.032 us; speedup vs baseline: 1.6738x; 1.0355x over previous
//
#include <hip/hip_runtime.h>
#include <math.h>

typedef unsigned int u32;
typedef __attribute__((ext_vector_type(8))) short bf16x8;
typedef __attribute__((ext_vector_type(4))) float f32x4;

#define NN   40000
#define EE   640000
#define SUBG 400
#define CELLS 100
#define BNEPS 1e-5f
#define GB    2048     // gather blocks
#define GEMMB 625
#define DEGB  512
#define FILLB 1024
#define SCALEB 2500    // NN*16 uint4 / 256

// ---- bf16 helpers ----
__device__ __forceinline__ u32 bf16pair(float a, float b) {
    u32 ua = __float_as_uint(a), ub = __float_as_uint(b);
    ua += 0x7fffu + ((ua >> 16) & 1u);
    ub += 0x7fffu + ((ub >> 16) & 1u);
    return (ua >> 16) | (ub & 0xffff0000u);
}
__device__ __forceinline__ float bflo(u32 u) { return __uint_as_float(u << 16); }
__device__ __forceinline__ float bfhi(u32 u) { return __uint_as_float(u & 0xffff0000u); }

// ---------------- init: zero deg/cursor + bf16-transpose weights + zero head stats ----------------
__global__ void k_init(int* deg_cursor, const float* W1, u32* Wt1,
                       const float* W2, u32* Wt2, const float* wa, u32* Wta,
                       float* hstats) {
    int i = blockIdx.x * 256 + threadIdx.x;
    if (i < 2 * NN) { deg_cursor[i] = 0; return; }
    i -= 2 * NN;
    if (i < 16384) {
        const float* W = (i < 8192) ? W1 : W2;
        u32* Wt = (i < 8192) ? Wt1 : Wt2;
        int j = i & 8191;
        int n = j >> 6, k2 = (j & 63) * 2;
        Wt[n * 64 + (j & 63)] = bf16pair(W[k2 * 128 + n], W[(k2 + 1) * 128 + n]);
        return;
    }
    i -= 16384;
    if (i < 4096) {
        int n = i >> 6, k2 = (i & 63) * 2;
        Wta[n * 64 + (i & 63)] = bf16pair(wa[k2 * 64 + n], wa[(k2 + 1) * 64 + n]);
        return;
    }
    i -= 4096;
    if (i < 320) hstats[i] = 0.f;
}

// ---------------- conv1 MFMA GEMM (unscaled) || degree count (merged dispatch) ----------------
__global__ __launch_bounds__(256)
void k_gemmdeg(const float* __restrict__ X, const u32* __restrict__ Wt,
               u32* __restrict__ Yb, const int* __restrict__ dst,
               int* __restrict__ deg) {
    int bid = blockIdx.x;
    int t = threadIdx.x;
    if (bid >= GEMMB) {
        int i = (bid - GEMMB) * 256 + t;
        int stride = DEGB * 256;
        for (; i < EE; i += stride) atomicAdd(&deg[dst[i]], 1);
        return;
    }
    int l = t & 63, wv = t >> 6;
    int rowbase = bid * 64 + wv * 16;
    int ml = l & 15, kg = l >> 4;

    f32x4 acc[8];
#pragma unroll
    for (int nt = 0; nt < 8; ++nt) acc[nt] = (f32x4){0.f, 0.f, 0.f, 0.f};
    const float* xr = X + (long)(rowbase + ml) * 128;
#pragma unroll
    for (int kk = 0; kk < 4; ++kk) {
        int k0 = kk * 32 + kg * 8;
        float4 xa = *(const float4*)&xr[k0];
        float4 xb = *(const float4*)&xr[k0 + 4];
        union { u32 u[4]; bf16x8 v; } af;
        af.u[0] = bf16pair(xa.x, xa.y);
        af.u[1] = bf16pair(xa.z, xa.w);
        af.u[2] = bf16pair(xb.x, xb.y);
        af.u[3] = bf16pair(xb.z, xb.w);
#pragma unroll
        for (int nt = 0; nt < 8; ++nt) {
            bf16x8 b = *(const bf16x8*)&Wt[(nt * 16 + ml) * 64 + (k0 >> 1)];
            acc[nt] = __builtin_amdgcn_mfma_f32_16x16x32_bf16(af.v, b, acc[nt], 0, 0, 0);
        }
    }
#pragma unroll
    for (int r = 0; r < 4; ++r) {
        int m = rowbase + kg * 4 + r;
        long obase = (long)m * 64;
#pragma unroll
        for (int nt = 0; nt < 8; ++nt) {
            float v = acc[nt][r];
            float v2 = __shfl_xor(v, 1);
            if ((l & 1) == 0)
                Yb[obase + nt * 8 + (ml >> 1)] = bf16pair(v, v2);
        }
    }
}

// ---------------- single-block full exclusive scan + dis (two-pass, no spill) ----------------
__global__ __launch_bounds__(1024)
void k_scan(const int* __restrict__ deg, int* __restrict__ rowstart,
            float* __restrict__ dis) {
    __shared__ int ps[1024];
    int t = threadIdx.x;
    const int4* d4 = (const int4*)deg;
    int sum = 0;
#pragma unroll
    for (int j = 0; j < 10; ++j) {
        int i4 = t * 10 + j;
        if (i4 < 10000) {
            int4 v = d4[i4];
            sum += v.x + v.y + v.z + v.w;
        }
    }
    ps[t] = sum;
    __syncthreads();
    for (int off = 1; off < 1024; off <<= 1) {
        int add = (t >= off) ? ps[t - off] : 0;
        __syncthreads();
        ps[t] += add;
        __syncthreads();
    }
    int run = ps[t] - sum;
#pragma unroll
    for (int j = 0; j < 10; ++j) {
        int i4 = t * 10 + j;
        if (i4 < 10000) {
            int4 v = d4[i4];
            int4 r;
            r.x = run;
            r.y = run + v.x;
            r.z = r.y + v.y;
            r.w = r.z + v.z;
            run = r.w + v.w;
            *(int4*)&rowstart[i4 * 4] = r;
            float4 dv;
            dv.x = rsqrtf((float)(v.x + 1));
            dv.y = rsqrtf((float)(v.y + 1));
            dv.z = rsqrtf((float)(v.z + 1));
            dv.w = rsqrtf((float)(v.w + 1));
            *(float4*)&dis[i4 * 4] = dv;
        }
    }
    if (t == 0) rowstart[NN] = EE;
}

// ---------------- fill CSR || scale Hb by dis (merged dispatch) ----------------
__global__ __launch_bounds__(256)
void k_fillscale(const int* __restrict__ src, const int* __restrict__ dst,
                 const int* __restrict__ rowstart, int* __restrict__ cursor,
                 int* __restrict__ csr_src, uint4* __restrict__ Hb,
                 const float* __restrict__ dis) {
    int bid = blockIdx.x;
    int t = threadIdx.x;
    if (bid < FILLB) {
        int i = bid * 256 + t;
        int stride = FILLB * 256;
        for (; i < EE; i += stride) {
            int d = dst[i];
            int slot = rowstart[d] + atomicAdd(&cursor[d], 1);
            csr_src[slot] = src[i];
        }
        return;
    }
    int i = (bid - FILLB) * 256 + t;   // uint4 index, NN*16 total
    float dd = dis[i >> 4];
    uint4 v = Hb[i];
    v.x = bf16pair(bflo(v.x) * dd, bfhi(v.x) * dd);
    v.y = bf16pair(bflo(v.y) * dd, bfhi(v.y) * dd);
    v.z = bf16pair(bflo(v.z) * dd, bfhi(v.z) * dd);
    v.w = bf16pair(bflo(v.w) * dd, bfhi(v.w) * dd);
    Hb[i] = v;
}

// ---------------- conv2 MFMA GEMM: bf16 input + fused BN1+ReLU, dis-prescaled out ----------------
__global__ __launch_bounds__(256)
void k_gemm_bf16(const u32* __restrict__ Xb, const u32* __restrict__ Wt,
                 u32* __restrict__ Yb, const float* __restrict__ ss,
                 const float* __restrict__ dis) {
    int t = threadIdx.x;
    int l = t & 63, wv = t >> 6;
    int rowbase = blockIdx.x * 64 + wv * 16;
    int ml = l & 15, kg = l >> 4;

    f32x4 acc[8];
#pragma unroll
    for (int nt = 0; nt < 8; ++nt) acc[nt] = (f32x4){0.f, 0.f, 0.f, 0.f};
    const u32* xr = Xb + (long)(rowbase + ml) * 64;
#pragma unroll
    for (int kk = 0; kk < 4; ++kk) {
        int k0 = kk * 32 + kg * 8;
        uint4 xw = *(const uint4*)&xr[k0 >> 1];
        float f0 = bflo(xw.x), f1 = bfhi(xw.x), f2 = bflo(xw.y), f3 = bfhi(xw.y);
        float f4 = bflo(xw.z), f5 = bfhi(xw.z), f6 = bflo(xw.w), f7 = bfhi(xw.w);
        float4 sca = *(const float4*)&ss[k0];
        float4 sha = *(const float4*)&ss[128 + k0];
        float4 scb = *(const float4*)&ss[k0 + 4];
        float4 shb = *(const float4*)&ss[128 + k0 + 4];
        f0 = fmaxf(fmaf(f0, sca.x, sha.x), 0.f);
        f1 = fmaxf(fmaf(f1, sca.y, sha.y), 0.f);
        f2 = fmaxf(fmaf(f2, sca.z, sha.z), 0.f);
        f3 = fmaxf(fmaf(f3, sca.w, sha.w), 0.f);
        f4 = fmaxf(fmaf(f4, scb.x, shb.x), 0.f);
        f5 = fmaxf(fmaf(f5, scb.y, shb.y), 0.f);
        f6 = fmaxf(fmaf(f6, scb.z, shb.z), 0.f);
        f7 = fmaxf(fmaf(f7, scb.w, shb.w), 0.f);
        union { u32 u[4]; bf16x8 v; } af;
        af.u[0] = bf16pair(f0, f1);
        af.u[1] = bf16pair(f2, f3);
        af.u[2] = bf16pair(f4, f5);
        af.u[3] = bf16pair(f6, f7);
#pragma unroll
        for (int nt = 0; nt < 8; ++nt) {
            bf16x8 b = *(const bf16x8*)&Wt[(nt * 16 + ml) * 64 + (k0 >> 1)];
            acc[nt] = __builtin_amdgcn_mfma_f32_16x16x32_bf16(af.v, b, acc[nt], 0, 0, 0);
        }
    }
#pragma unroll
    for (int r = 0; r < 4; ++r) {
        int m = rowbase + kg * 4 + r;
        float dd = dis[m];
        long obase = (long)m * 64;
#pragma unroll
        for (int nt = 0; nt < 8; ++nt) {
            float v = acc[nt][r] * dd;
            float v2 = __shfl_xor(v, 1);
            if ((l & 1) == 0)
                Yb[obase + nt * 8 + (ml >> 1)] = bf16pair(v, v2);
        }
    }
}

// ---------------- gather + fused BN partial stats ----------------
__global__ __launch_bounds__(256)
void k_gather_stats(const uint4* __restrict__ Hb, const int* __restrict__ rowstart,
                    const int* __restrict__ csr_src, const float* __restrict__ dis,
                    const float* __restrict__ bias, u32* __restrict__ F1b,
                    float* __restrict__ part) {
    __shared__ float ls[1024], lq[1024];
    int t = threadIdx.x;
    int lane = t & 63, wv = t >> 6;
    int gw = blockIdx.x * 4 + wv;
    int g = lane >> 4, p = lane & 15;
    int c0 = p * 8 + g * 2;
    float2 bb = *(const float2*)&bias[c0];
    float s0 = 0.f, s1 = 0.f, q0 = 0.f, q1 = 0.f;

    for (int node = gw; node < NN; node += GB * 4) {
        float a0 = 0.f, a1 = 0.f, a2 = 0.f, a3 = 0.f, a4 = 0.f, a5 = 0.f, a6 = 0.f, a7 = 0.f;
        if (g == 0) {
            uint4 h = Hb[node * 16 + p];
            a0 = bflo(h.x); a1 = bfhi(h.x);
            a2 = bflo(h.y); a3 = bfhi(h.y);
            a4 = bflo(h.z); a5 = bfhi(h.z);
            a6 = bflo(h.w); a7 = bfhi(h.w);
        }
        int e1 = rowstart[node + 1];
        int e = rowstart[node] + g;
        for (; e + 4 < e1; e += 8) {
            int sA = csr_src[e];
            int sB = csr_src[e + 4];
            uint4 h0 = Hb[sA * 16 + p];
            uint4 h1 = Hb[sB * 16 + p];
            a0 += bflo(h0.x); a1 += bfhi(h0.x);
            a2 += bflo(h0.y); a3 += bfhi(h0.y);
            a4 += bflo(h0.z); a5 += bfhi(h0.z);
            a6 += bflo(h0.w); a7 += bfhi(h0.w);
            a0 += bflo(h1.x); a1 += bfhi(h1.x);
            a2 += bflo(h1.y); a3 += bfhi(h1.y);
            a4 += bflo(h1.z); a5 += bfhi(h1.z);
            a6 += bflo(h1.w); a7 += bfhi(h1.w);
        }
        if (e < e1) {
            int sA = csr_src[e];
            uint4 h0 = Hb[sA * 16 + p];
            a0 += bflo(h0.x); a1 += bfhi(h0.x);
            a2 += bflo(h0.y); a3 += bfhi(h0.y);
            a4 += bflo(h0.z); a5 += bfhi(h0.z);
            a6 += bflo(h0.w); a7 += bfhi(h0.w);
        }
#pragma unroll
        for (int m = 16; m <= 32; m <<= 1) {
            a0 += __shfl_xor(a0, m); a1 += __shfl_xor(a1, m);
            a2 += __shfl_xor(a2, m); a3 += __shfl_xor(a3, m);
            a4 += __shfl_xor(a4, m); a5 += __shfl_xor(a5, m);
            a6 += __shfl_xor(a6, m); a7 += __shfl_xor(a7, m);
        }
        float dd = dis[node];
        float x = (g == 0) ? a0 : (g == 1) ? a2 : (g == 2) ? a4 : a6;
        float y = (g == 0) ? a1 : (g == 1) ? a3 : (g == 2) ? a5 : a7;
        x = fmaf(x, dd, bb.x);
        y = fmaf(y, dd, bb.y);
        u32 pw = bf16pair(x, y);
        F1b[node * 64 + (c0 >> 1)] = pw;
        float rx = bflo(pw), ry = bfhi(pw);
        s0 += rx; s1 += ry; q0 += rx * rx; q1 += ry * ry;
    }
    ls[wv * 128 + c0] = s0; ls[wv * 128 + c0 + 1] = s1;
    lq[wv * 128 + c0] = q0; lq[wv * 128 + c0 + 1] = q1;
    __syncthreads();
    if (t < 128) {
        float S = ls[t] + ls[128 + t] + ls[256 + t] + ls[384 + t];
        float Q = lq[t] + lq[128 + t] + lq[256 + t] + lq[384 + t];
        part[blockIdx.x * 256 + t] = S;
        part[blockIdx.x * 256 + 128 + t] = Q;
    }
}

// ---------------- BN finalize from gather partials ----------------
__global__ __launch_bounds__(256)
void k_bnfinalw(const float* __restrict__ part, const float* __restrict__ g,
                const float* __restrict__ b, float* __restrict__ ss) {
    __shared__ float rs[256], rq[256];
    int c = blockIdx.x, t = threadIdx.x;
    float s = 0.f, q = 0.f;
    for (int i = t; i < GB; i += 256) {
        s += part[i * 256 + c];
        q += part[i * 256 + 128 + c];
    }
    rs[t] = s; rq[t] = q;
    __syncthreads();
    for (int off = 128; off > 0; off >>= 1) {
        if (t < off) { rs[t] += rs[t + off]; rq[t] += rq[t + off]; }
        __syncthreads();
    }
    if (t == 0) {
        float mean = rs[0] * (1.0f / NN);
        float var  = rq[0] * (1.0f / NN) - mean * mean;
        float sc = g[c] * rsqrtf(var + BNEPS);
        ss[c] = sc;
        ss[128 + c] = b[c] - mean * sc;
    }
}

// ---------------- k_scoremb: BN2+ReLU (regs) + emb write + MFMA attention scores ----------------
// 625 blocks x 256 threads; wave = 16 genes; no LDS.
__global__ __launch_bounds__(256)
void k_scoremb(const u32* __restrict__ F1b, const float* __restrict__ ss,
               float* __restrict__ emb,
               const u32* __restrict__ Wta, const float* __restrict__ b1,
               const float* __restrict__ w2, const float* __restrict__ b2,
               float* __restrict__ scores) {
    int t = threadIdx.x;
    int l = t & 63, wv = t >> 6;
    int rowbase = blockIdx.x * 64 + wv * 16;
    int ml = l & 15, kg = l >> 4;

    f32x4 acc[4];
#pragma unroll
    for (int nt = 0; nt < 4; ++nt) acc[nt] = (f32x4){0.f, 0.f, 0.f, 0.f};
    const u32* xr = F1b + (long)(rowbase + ml) * 64;
    float* er = emb + (long)(rowbase + ml) * 128;
#pragma unroll
    for (int kk = 0; kk < 4; ++kk) {
        int k0 = kk * 32 + kg * 8;
        uint4 xw = *(const uint4*)&xr[k0 >> 1];
        float f0 = bflo(xw.x), f1 = bfhi(xw.x), f2 = bflo(xw.y), f3 = bfhi(xw.y);
        float f4 = bflo(xw.z), f5 = bfhi(xw.z), f6 = bflo(xw.w), f7 = bfhi(xw.w);
        float4 sca = *(const float4*)&ss[k0];
        float4 sha = *(const float4*)&ss[128 + k0];
        float4 scb = *(const float4*)&ss[k0 + 4];
        float4 shb = *(const float4*)&ss[128 + k0 + 4];
        f0 = fmaxf(fmaf(f0, sca.x, sha.x), 0.f);
        f1 = fmaxf(fmaf(f1, sca.y, sha.y), 0.f);
        f2 = fmaxf(fmaf(f2, sca.z, sha.z), 0.f);
        f3 = fmaxf(fmaf(f3, sca.w, sha.w), 0.f);
        f4 = fmaxf(fmaf(f4, scb.x, shb.x), 0.f);
        f5 = fmaxf(fmaf(f5, scb.y, shb.y), 0.f);
        f6 = fmaxf(fmaf(f6, scb.z, shb.z), 0.f);
        f7 = fmaxf(fmaf(f7, scb.w, shb.w), 0.f);
        float4 e0 = { f0, f1, f2, f3 };
        float4 e1 = { f4, f5, f6, f7 };
        *(float4*)&er[k0] = e0;
        *(float4*)&er[k0 + 4] = e1;
        union { u32 u[4]; bf16x8 v; } af;
        af.u[0] = bf16pair(f0, f1);
        af.u[1] = bf16pair(f2, f3);
        af.u[2] = bf16pair(f4, f5);
        af.u[3] = bf16pair(f6, f7);
#pragma unroll
        for (int nt = 0; nt < 4; ++nt) {
            bf16x8 b = *(const bf16x8*)&Wta[(nt * 16 + ml) * 64 + (k0 >> 1)];
            acc[nt] = __builtin_amdgcn_mfma_f32_16x16x32_bf16(af.v, b, acc[nt], 0, 0, 0);
        }
    }
    float b1v[4], w2v[4];
#pragma unroll
    for (int nt = 0; nt < 4; ++nt) {
        b1v[nt] = b1[nt * 16 + ml];
        w2v[nt] = w2[nt * 16 + ml];
    }
    float b2v = b2[0];
#pragma unroll
    for (int r = 0; r < 4; ++r) {
        float s = tanhf(acc[0][r] + b1v[0]) * w2v[0]
                + tanhf(acc[1][r] + b1v[1]) * w2v[1]
                + tanhf(acc[2][r] + b1v[2]) * w2v[2]
                + tanhf(acc[3][r] + b1v[3]) * w2v[3];
        s += __shfl_xor(s, 1);
        s += __shfl_xor(s, 2);
        s += __shfl_xor(s, 4);
        s += __shfl_xor(s, 8);
        if (ml == 0) scores[rowbase + kg * 4 + r] = s + b2v;
    }
}

// ---------------- k_pool4: softmax (redundant per quarter) + partial pool ----------------
// 400 blocks = 4 per cell; block handles 100 genes; partials -> pp[b][128]
__global__ __launch_bounds__(256)
void k_pool4(const u32* __restrict__ F1b, const float* __restrict__ ss,
             const float* __restrict__ scores, float* __restrict__ pp) {
    __shared__ float sl[SUBG];
    __shared__ float red[256];
    __shared__ float rbuf[512];
    int b = blockIdx.x;
    int c = b >> 2, q = b & 3;
    int t = threadIdx.x;
    int base = c * SUBG;

    float lmax = -1e30f;
    for (int i = t; i < SUBG; i += 256) {
        float v = scores[base + i];
        sl[i] = v;
        lmax = fmaxf(lmax, v);
    }
    red[t] = lmax;
    __syncthreads();
    for (int off = 128; off > 0; off >>= 1) {
        if (t < off) red[t] = fmaxf(red[t], red[t + off]);
        __syncthreads();
    }
    float mx = red[0];
    __syncthreads();
    float lsum = 0.f;
    for (int i = t; i < SUBG; i += 256) {
        float e = __expf(sl[i] - mx);
        sl[i] = e;
        lsum += e;
    }
    red[t] = lsum;
    __syncthreads();
    for (int off = 128; off > 0; off >>= 1) {
        if (t < off) red[t] += red[t + off];
        __syncthreads();
    }
    float inv = 1.0f / red[0];
    __syncthreads();

    // pool this quarter's 100 genes: thread = colpair cc x gene-group gp (25 genes)
    int cc = t & 63, gp = t >> 6;
    float2 scv = *(const float2*)&ss[2 * cc];
    float2 shv = *(const float2*)&ss[128 + 2 * cc];
    int g0 = q * 100 + gp * 25;
    float a0 = 0.f, a1 = 0.f;
#pragma unroll 5
    for (int j = 0; j < 25; ++j) {
        int gg = g0 + j;
        u32 v = F1b[(long)(base + gg) * 64 + cc];
        float w = sl[gg] * inv;
        float x0 = fmaxf(fmaf(bflo(v), scv.x, shv.x), 0.f);
        float x1 = fmaxf(fmaf(bfhi(v), scv.y, shv.y), 0.f);
        a0 += w * x0;
        a1 += w * x1;
    }
    rbuf[gp * 128 + 2 * cc] = a0;
    rbuf[gp * 128 + 2 * cc + 1] = a1;
    __syncthreads();
    if (t < 128)
        pp[b * 128 + t] = rbuf[t] + rbuf[128 + t] + rbuf[256 + t] + rbuf[384 + t];
}

// ---------------- k_head1r: sum quarters + fc head1 + atomic BN stats ----------------
__global__ __launch_bounds__(128)
void k_head1r(const float* __restrict__ pp, const float* __restrict__ fc_w,
              const float* __restrict__ fc_b, float* __restrict__ y1pre,
              float* __restrict__ hstats) {
    __shared__ float pr[128];
    int c = blockIdx.x, t = threadIdx.x;
    pr[t] = pp[(c * 4 + 0) * 128 + t] + pp[(c * 4 + 1) * 128 + t]
          + pp[(c * 4 + 2) * 128 + t] + pp[(c * 4 + 3) * 128 + t];
    __syncthreads();
    float a1 = fc_b[t];
#pragma unroll 4
    for (int k = 0; k < 128; ++k) a1 = fmaf(pr[k], fc_w[k * 128 + t], a1);
    y1pre[c * 128 + t] = a1;
    atomicAdd(&hstats[t], a1);
    atomicAdd(&hstats[128 + t], a1 * a1);
}

// ---------------- head2: finalize BN-e, apply, bottleneck, atomic stats2 ----------------
__global__ __launch_bounds__(128)
void k_head2s(const float* __restrict__ y1pre, const float* __restrict__ hstats,
              const float* __restrict__ bne_g, const float* __restrict__ bne_b,
              const float* __restrict__ bot_w, const float* __restrict__ bot_b,
              float* __restrict__ y2pre, float* __restrict__ hstats2) {
    __shared__ float row[128];
    int c = blockIdx.x, t = threadIdx.x;
    float s = hstats[t], q = hstats[128 + t];
    float mean = s * 0.01f, var = q * 0.01f - mean * mean;
    float scv = bne_g[t] * rsqrtf(var + BNEPS);
    float shv = bne_b[t] - mean * scv;
    row[t] = fmaxf(fmaf(y1pre[c * 128 + t], scv, shv), 0.f);
    __syncthreads();
    if (t < 32) {
        float a2 = bot_b[t];
#pragma unroll 4
        for (int k = 0; k < 128; ++k) a2 = fmaf(row[k], bot_w[k * 32 + t], a2);
        y2pre[c * 32 + t] = a2;
        atomicAdd(&hstats2[t], a2);
        atomicAdd(&hstats2[32 + t], a2 * a2);
    }
}

// ---------------- final: BN-b finalize + apply ----------------
__global__ __launch_bounds__(256)
void k_out(const float* __restrict__ y2pre, const float* __restrict__ hstats2,
           const float* __restrict__ bnb_g, const float* __restrict__ bnb_b,
           float* __restrict__ y_out) {
    __shared__ float scv[32], shv[32];
    int t = threadIdx.x;
    if (t < 32) {
        float s = hstats2[t], q = hstats2[32 + t];
        float mean = s * 0.01f, var = q * 0.01f - mean * mean;
        float v = bnb_g[t] * rsqrtf(var + BNEPS);
        scv[t] = v; shv[t] = bnb_b[t] - mean * v;
    }
    __syncthreads();
    for (int i = t; i < CELLS * 32; i += 256)
        y_out[i] = fmaxf(fmaf(y2pre[i], scv[i & 31], shv[i & 31]), 0.f);
}

// ---------------- launcher ----------------
extern "C" void kernel_launch(void* const* d_in, const int* in_sizes, int n_in,
                              void* d_out, int out_size, void* d_ws, size_t ws_size,
                              hipStream_t stream) {
    const float* x        = (const float*)d_in[0];
    const int*   ei       = (const int*)d_in[1];
    const float* conv1_w  = (const float*)d_in[2];
    const float* conv1_b  = (const float*)d_in[3];
    const float* bn1_g    = (const float*)d_in[4];
    const float* bn1_b    = (const float*)d_in[5];
    const float* conv2_w  = (const float*)d_in[6];
    const float* conv2_b  = (const float*)d_in[7];
    const float* bn2_g    = (const float*)d_in[8];
    const float* bn2_b    = (const float*)d_in[9];
    const float* att_w1   = (const float*)d_in[10];
    const float* att_b1   = (const float*)d_in[11];
    const float* att_w2   = (const float*)d_in[12];
    const float* att_b2   = (const float*)d_in[13];
    const float* fc_w     = (const float*)d_in[14];
    const float* fc_b     = (const float*)d_in[15];
    const float* bne_g    = (const float*)d_in[16];
    const float* bne_b    = (const float*)d_in[17];
    const float* bot_w    = (const float*)d_in[18];
    const float* bot_b    = (const float*)d_in[19];
    const float* bnb_g    = (const float*)d_in[20];
    const float* bnb_b    = (const float*)d_in[21];

    const int* src = ei;
    const int* dst = ei + EE;

    float* y_out   = (float*)d_out;            // [100,32]
    float* emb_out = y_out + CELLS * 32;       // [40000,128]

    float* ws = (float*)d_ws;
    u32*   Hb     = (u32*)ws;                  // N*64
    u32*   F1b    = Hb + (long)NN * 64;        // N*64
    float* dis    = (float*)(F1b + (long)NN * 64);  // N
    float* part   = dis + NN;                  // GB*256
    float* ss     = part + GB * 256;           // 256
    float* hstats = ss + 256;                  // 320
    float* y1pre  = hstats + 320;              // C*128
    float* y2pre  = y1pre + CELLS * 128;       // C*32
    float* scores = y2pre + CELLS * 32;        // N
    float* pp     = scores + NN;               // 400*128
    u32*   Wt1    = (u32*)(pp + 400 * 128);    // 8192
    u32*   Wt2    = Wt1 + 8192;                // 8192
    u32*   Wta    = Wt2 + 8192;                // 4096
    int*   deg    = (int*)(Wta + 4096);        // N (deg + cursor contiguous)
    int*   cursor = deg + NN;                  // N
    int*   rowstart = cursor + NN;             // N+1
    int*   csr_src  = rowstart + NN + 1;       // E

    // 1. init
    k_init<<<394, 256, 0, stream>>>(deg, conv1_w, Wt1, conv2_w, Wt2, att_w1, Wta, hstats);
    // 2. conv1 GEMM (unscaled) || degree count
    k_gemmdeg<<<GEMMB + DEGB, 256, 0, stream>>>(x, Wt1, Hb, dst, deg);
    // 3. scan -> rowstart, dis
    k_scan<<<1, 1024, 0, stream>>>(deg, rowstart, dis);
    // 4. fill CSR || scale Hb by dis
    k_fillscale<<<FILLB + SCALEB, 256, 0, stream>>>(src, dst, rowstart, cursor,
                                                    csr_src, (uint4*)Hb, dis);
    // 5-6. conv1 gather+stats, BN1 finalize
    k_gather_stats<<<GB, 256, 0, stream>>>((const uint4*)Hb, rowstart, csr_src, dis,
                                           conv1_b, F1b, part);
    k_bnfinalw<<<128, 256, 0, stream>>>(part, bn1_g, bn1_b, ss);
    // 7. conv2 GEMM (bf16 in, BN1+ReLU fused, dis-prescaled out)
    k_gemm_bf16<<<GEMMB, 256, 0, stream>>>(F1b, Wt2, Hb, ss, dis);
    // 8-9. conv2 gather+stats, BN2 finalize
    k_gather_stats<<<GB, 256, 0, stream>>>((const uint4*)Hb, rowstart, csr_src, dis,
                                           conv2_b, F1b, part);
    k_bnfinalw<<<128, 256, 0, stream>>>(part, bn2_g, bn2_b, ss);
    // 10. BN2+ReLU + emb + MFMA scores
    k_scoremb<<<GEMMB, 256, 0, stream>>>(F1b, ss, emb_out, Wta, att_b1, att_w2,
                                         att_b2, scores);
    // 11. softmax + partial pool (4 blocks/cell)
    k_pool4<<<4 * CELLS, 256, 0, stream>>>(F1b, ss, scores, pp);
    // 12. sum partials + head1
    k_head1r<<<CELLS, 128, 0, stream>>>(pp, fc_w, fc_b, y1pre, hstats);
    // 13. head2 + stats2
    k_head2s<<<CELLS, 128, 0, stream>>>(y1pre, hstats, bne_g, bne_b, bot_w, bot_b,
                                        y2pre, hstats + 256);
    // 14. final BN + output
    k_out<<<1, 256, 0, stream>>>(y2pre, hstats + 256, bnb_g, bnb_b, y_out);
}